// Round 21
// baseline (86.765 us; speedup 1.0000x reference)
//
#include <hip/hip_runtime.h>
#include <math.h>

#define CC 256
#define HEADS 8
#define DD 32
#define GG 48
#define LL (GG*GG)      // 2304
#define NB 2
#define PTAB_N 95

typedef float f32x4 __attribute__((ext_vector_type(4)));
typedef _Float16 f16x8 __attribute__((ext_vector_type(8)));
typedef _Float16 f16x4 __attribute__((ext_vector_type(4)));

// workspace layout (floats).
// vbT/ebT live in the old xs region. xh aliases ao (dead before attn writes ao).
// po (fp16) aliases qb (qb dead after attn).
#define OFF_XS   0
#define SZ_XS    (NB*CC*LL)           // 1,179,648
#define OFF_VBT  OFF_XS               // 786,432 floats (fp16 x 1,572,864)
#define OFF_EBT  (OFF_XS + 786432)    // 24,576 floats (fp16 x 49,152)
#define OFF_QB   (OFF_XS + SZ_XS)
#define SZ_QB    (NB*LL*CC)           // 1,179,648
#define OFF_PO   OFF_QB
#define OFF_VT   (OFF_QB + SZ_QB)
#define SZ_VT_F  (NB*CC*LL/2)         // vtb fp16, 589,824 floats
#define OFF_AO   (OFF_VT + SZ_VT_F)
#define OFF_XH   OFF_AO               // xh fp16 aliases ao
#define SZ_AO    (NB*LL*CC)
#define OFF_EB   (OFF_AO + SZ_AO)
#define SZ_EB    (NB*HEADS*LL)
#define OFF_PTX  (OFF_EB + SZ_EB)
#define SZ_PT    (PTAB_N*CC)
#define OFF_PTY  (OFF_PTX + SZ_PT)
#define OFF_WB   (OFF_PTY + SZ_PT)

// ---------------- fused extract+convert: x (strided) -> xh fp16 swizzled ------
__global__ void k_xin(const float* __restrict__ x, _Float16* __restrict__ xh) {
    const int n = blockIdx.z, c0 = blockIdx.y*64, s0 = blockIdx.x*64;
    const int t = threadIdx.x;
    __shared__ _Float16 ldt[64*72];   // [s][c], row stride 72
    #pragma unroll
    for (int l = 0; l < 4; ++l) {
        int idx = t + 256*l;          // 0..1023
        int cl = idx >> 4, s4 = idx & 15;
        const float* xb = x + (size_t)(n*CC + c0+cl)*96*96;
        #pragma unroll
        for (int e = 0; e < 4; ++e) {
            int s = s0 + s4*4 + e;
            int h = s / GG, w = s % GG;
            ldt[(s4*4+e)*72 + cl] = (_Float16)xb[(2*h)*96 + 2*w];
        }
    }
    __syncthreads();
    #pragma unroll
    for (int l = 0; l < 2; ++l) {
        int idx = t + 256*l;          // 0..511
        int sl = idx >> 3, jg = idx & 7;
        f16x8 o = *(const f16x8*)(ldt + sl*72 + jg*8);
        int s = s0 + sl;
        int p = ((c0 >> 3) + jg) ^ (s & 7);
        *(f16x8*)(xh + (size_t)(n*LL + s)*CC + p*8) = o;
    }
}

// ---------------- merged prep: ptab (y=0,1) + wb (y=2, blocks 0..7) -----------
__global__ void k_prep(const float* __restrict__ Wgx, const float* __restrict__ Wgy,
                       const float* __restrict__ Wk, const float* __restrict__ ab,
                       float* __restrict__ ptx, float* __restrict__ pty,
                       float* __restrict__ wb) {
    const int which = blockIdx.y;
    const int t = threadIdx.x;
    if (which == 2) {
        int i = blockIdx.x;
        if (i < HEADS) {
            float acc = 0.f;
            for (int d = 0; d < DD; ++d) acc += ab[i*DD+d] * Wk[(i*DD+d)*CC + t];
            wb[i*CC + t] = acc;
        }
        return;
    }
    __shared__ float emb[128];
    int ddv = blockIdx.x;
    float diff = 2.0f * (float)(ddv - 47);
    if (t < 64) {
        float dim = powf(1000.0f, (float)t / 64.0f);
        float ang = diff / dim;
        emb[t]      = sinf(ang);
        emb[t + 64] = cosf(ang);
    }
    __syncthreads();
    const float* Wg = which ? Wgy : Wgx;
    float* pt = which ? pty : ptx;
    float acc = 0.f;
    #pragma unroll 8
    for (int e = 0; e < 128; ++e) acc += emb[e] * Wg[t*128 + e];
    pt[ddv*CC + t] = acc * 0.70710678118654752f;
}

// ---------------- MFMA GEMM: A=[Wq;Wv;wb;0] (576x256) @ xh^T -> qb/vtb/ebx ----
__global__ __launch_bounds__(256) void k_gemm_qv(const float* __restrict__ Wq,
                                                 const float* __restrict__ Wv,
                                                 const float* __restrict__ wb,
                                                 const _Float16* __restrict__ xh,
                                                 float* __restrict__ qb,
                                                 _Float16* __restrict__ vtb,
                                                 float* __restrict__ ebx) {
    const int n  = blockIdx.z;
    const int my = blockIdx.y;           // 0..8: m0 = my*64
    const int j0 = blockIdx.x * 64;      // token tile
    const int t = threadIdx.x;
    const int lane = t & 63, mw = t >> 6;
    __shared__ alignas(16) _Float16 As[64*256];
    __shared__ alignas(16) _Float16 Bs[64*256];

    #pragma unroll
    for (int l = 0; l < 8; ++l) {
        int idx = t + 256*l;             // 0..2047
        int m = idx >> 5, j = idx & 31;
        int row = my*64 + m;
        f16x8 h = {};
        if (row < 520) {
            const float* src = (row < 256) ? (Wq + (size_t)row*CC + j*8)
                             : (row < 512) ? (Wv + (size_t)(row-256)*CC + j*8)
                                           : (wb + (size_t)(row-512)*CC + j*8);
            float4 v0 = *(const float4*)(src);
            float4 v1 = *(const float4*)(src + 4);
            h[0]=(_Float16)v0.x; h[1]=(_Float16)v0.y;
            h[2]=(_Float16)v0.z; h[3]=(_Float16)v0.w;
            h[4]=(_Float16)v1.x; h[5]=(_Float16)v1.y;
            h[6]=(_Float16)v1.z; h[7]=(_Float16)v1.w;
        }
        *(f16x8*)(As + m*256 + ((j ^ (m&7))*8)) = h;
    }
    {
        const _Float16* src = xh + (size_t)(n*LL + j0)*CC + mw*4096 + lane*8;
        _Float16* dst = Bs + mw*4096;
        #pragma unroll
        for (int c = 0; c < 8; ++c)
            __builtin_amdgcn_global_load_lds(src + c*512, dst + c*512, 16, 0, 0);
    }
    __syncthreads();

    const int r = lane & 15, g = lane >> 4;
    f16x8 af[8];
    #pragma unroll
    for (int kk = 0; kk < 8; ++kk)
        af[kk] = *(const f16x8*)(As + (mw*16 + r)*256 + (((kk*4+g) ^ (r&7))*8));
    f32x4 acc0 = {}, acc1 = {}, acc2 = {}, acc3 = {};
    #pragma unroll
    for (int kk = 0; kk < 8; ++kk) {
        f16x8 b0 = *(const f16x8*)(Bs + (0*16 + r)*256 + (((kk*4+g) ^ (r&7))*8));
        f16x8 b1 = *(const f16x8*)(Bs + (1*16 + r)*256 + (((kk*4+g) ^ (r&7))*8));
        f16x8 b2 = *(const f16x8*)(Bs + (2*16 + r)*256 + (((kk*4+g) ^ (r&7))*8));
        f16x8 b3 = *(const f16x8*)(Bs + (3*16 + r)*256 + (((kk*4+g) ^ (r&7))*8));
        acc0 = __builtin_amdgcn_mfma_f32_16x16x32_f16(af[kk], b0, acc0, 0,0,0);
        acc1 = __builtin_amdgcn_mfma_f32_16x16x32_f16(af[kk], b1, acc1, 0,0,0);
        acc2 = __builtin_amdgcn_mfma_f32_16x16x32_f16(af[kk], b2, acc2, 0,0,0);
        acc3 = __builtin_amdgcn_mfma_f32_16x16x32_f16(af[kk], b3, acc3, 0,0,0);
    }

    const int rowD = mw*16 + g*4;
    #pragma unroll
    for (int nf = 0; nf < 4; ++nf) {
        const f32x4& a = (nf==0)?acc0:(nf==1)?acc1:(nf==2)?acc2:acc3;
        int token = j0 + nf*16 + r;
        #pragma unroll
        for (int reg = 0; reg < 4; ++reg) {
            int row = my*64 + rowD + reg;
            float v = a[reg];
            if (my < 4) {
                qb[(size_t)(n*LL + token)*CC + row] = v;
            } else if (my < 8) {
                vtb[(size_t)(n*CC + row - 256)*LL + token] = (_Float16)v;
            } else {
                int i = row - 512;
                if (i < 8) ebx[(size_t)(n*HEADS + i)*LL + token] = __expf(v);
            }
        }
    }
}

// ---------------- transpose V to u-contiguous, fold eb, XOR-swizzled ----------
__global__ void k_vtr(const _Float16* __restrict__ vtb, const float* __restrict__ ebx,
                      _Float16* __restrict__ vbT, _Float16* __restrict__ ebT) {
    const int ni = blockIdx.x;
    const int pair = blockIdx.y*256 + threadIdx.x;   // [0,1536)
    const int v = pair >> 5, d = pair & 31;
    const int sw = d & 7;
    const _Float16* vsrc = vtb + (size_t)(ni*32 + d)*LL;
    const float*  ebs  = ebx + (size_t)ni*LL;
    _Float16* dst = vbT + (size_t)ni*98304 + (size_t)(v*32 + d)*64;
    f16x8 z = {};
    #pragma unroll
    for (int c = 0; c < 6; ++c) {
        f16x8 o;
        #pragma unroll
        for (int e = 0; e < 8; ++e) {
            int u = c*8 + e;
            o[e] = (_Float16)((float)vsrc[u*48 + v] * ebs[u*48 + v]);
        }
        *(f16x8*)(dst + (c ^ sw)*8) = o;
    }
    *(f16x8*)(dst + (6 ^ sw)*8) = z;
    *(f16x8*)(dst + (7 ^ sw)*8) = z;
    if (d == 0) {
        _Float16* ed = ebT + (size_t)ni*3072 + (size_t)v*64;
        #pragma unroll
        for (int c = 0; c < 6; ++c) {
            f16x8 o;
            #pragma unroll
            for (int e = 0; e < 8; ++e)
                o[e] = (_Float16)ebs[(c*8+e)*48 + v];
            *(f16x8*)(ed + c*8) = o;
        }
        *(f16x8*)(ed + 48) = z;
        *(f16x8*)(ed + 56) = z;
    }
}

// ---------------- attention v9: 32-row q-tiles (2x grid), d-half per wave -----
// wave mw: q-rows (mw&1)*16..+16, d-half dh = mw>>1. Grid 1152 blocks -> ~4/CU.
__global__ __launch_bounds__(256) void k_attn(const float* __restrict__ qb,
                                              const _Float16* __restrict__ vbT,
                                              const _Float16* __restrict__ ebT,
                                              const float* __restrict__ ptx,
                                              const float* __restrict__ pty,
                                              float* __restrict__ ao) {
    const int t = threadIdx.x;
    const int lane = t & 63;
    const int mw = t >> 6;
    const int ni = blockIdx.y;
    const int n = ni >> 3, i = ni & 7;
    const int s0 = blockIdx.x * 32;

    // overlay pool: phase1 {qs 4KB, pts 15.2KB} / main {Vt dbuf 2x16KB}
    __shared__ alignas(16) char smpool[32768];
    float*    qs  = (float*)smpool;                 // [1024]
    _Float16* pts = (_Float16*)(smpool + 4096);     // [2][95][40]
    _Float16* Vt  = (_Float16*)smpool;              // [2][8192]
    __shared__ alignas(16) _Float16 Exs[32*56];     // exp(ex-mex) fp16, stride 56
    __shared__ alignas(16) _Float16 Eys[32*72];     // exp(ey-mey) fp16, u-pad 64

    // phase 0: stage Q tile (32 rows) + fp16 head-slices of pos tables
    {
        int r4 = t >> 3, dq = t & 7;
        float4 v4 = *(const float4*)(qb + (size_t)(n*LL + s0 + r4)*CC + i*32 + dq*4);
        *(float4*)(&qs[r4*32 + dq*4]) = v4;
    }
    for (int idx = t; idx < 2*PTAB_N*8; idx += 256) {
        int which = idx / (PTAB_N*8);
        int rem = idx % (PTAB_N*8);
        int ddv = rem >> 3, f4 = rem & 7;
        const float* src = (which ? ptx : pty) + (size_t)ddv*CC + i*32 + f4*4;
        float4 v = *(const float4*)src;
        f16x4 hh;
        hh[0]=(_Float16)v.x; hh[1]=(_Float16)v.y;
        hh[2]=(_Float16)v.z; hh[3]=(_Float16)v.w;
        *(f16x4*)(pts + which*(PTAB_N*40) + ddv*40 + f4*4) = hh;
    }
    __syncthreads();

    // phase 1: one q-row per 8 threads; 6 ey + 6 ex dots each; 8-lane max
    {
        const int rr = t >> 3, pp = t & 7;
        const int s = s0 + rr, h = s / GG, w = s % GG;
        float4 qreg[8];
        #pragma unroll
        for (int d4 = 0; d4 < 8; ++d4) qreg[d4] = *(const float4*)(qs + rr*32 + d4*4);
        float eyv[6], exv[6];
        float mey = -1e30f, mex = -1e30f;
        #pragma unroll
        for (int k = 0; k < 12; ++k) {
            int j = pp + 8*(k < 6 ? k : k-6);
            const _Float16* tp;
            if (k < 6) tp = pts + (h - j + 47)*40;
            else       tp = pts + PTAB_N*40 + (w - j + 47)*40;
            float acc = 0.f;
            #pragma unroll
            for (int d8 = 0; d8 < 4; ++d8) {
                f16x8 b = *(const f16x8*)(tp + d8*8);
                float4 a1v = qreg[2*d8], a2v = qreg[2*d8+1];
                acc += a1v.x*(float)b[0] + a1v.y*(float)b[1]
                     + a1v.z*(float)b[2] + a1v.w*(float)b[3]
                     + a2v.x*(float)b[4] + a2v.y*(float)b[5]
                     + a2v.z*(float)b[6] + a2v.w*(float)b[7];
            }
            if (k < 6) { eyv[k] = acc;   mey = fmaxf(mey, acc); }
            else       { exv[k-6] = acc; mex = fmaxf(mex, acc); }
        }
        mey = fmaxf(mey, __shfl_xor(mey, 1, 64));
        mey = fmaxf(mey, __shfl_xor(mey, 2, 64));
        mey = fmaxf(mey, __shfl_xor(mey, 4, 64));
        mex = fmaxf(mex, __shfl_xor(mex, 1, 64));
        mex = fmaxf(mex, __shfl_xor(mex, 2, 64));
        mex = fmaxf(mex, __shfl_xor(mex, 4, 64));
        #pragma unroll
        for (int k = 0; k < 6; ++k) {
            Eys[rr*72 + pp + 8*k] = (_Float16)__expf(eyv[k] - mey);
            Exs[rr*56 + pp + 8*k] = (_Float16)__expf(exv[k] - mex);
        }
    }
    // zero-pad Ey u 48..63
    for (int zi = t; zi < 32*16; zi += 256) {
        int r = zi >> 4, c = zi & 15;
        Eys[r*72 + 48 + c] = (_Float16)0.f;
    }
    __syncthreads();

    const int r = lane & 15, g = lane >> 4;
    const int dh = mw >> 1;              // d-half owned by this wave
    const int rowA = (mw & 1)*16 + r;    // A-frag q-row
    const int rowD = (mw & 1)*16 + g*4;  // D rows rowD..rowD+3

    f16x8 a0 = *(const f16x8*)(Eys + rowA*72 + g*8);
    f16x8 a1 = *(const f16x8*)(Eys + rowA*72 + 32 + g*8);

    const _Float16* vb = vbT + (size_t)ni*(48*32*64);
    const _Float16* et = ebT + (size_t)ni*(48*64);

    // HS = Ey' @ ebT  (3 n-frags of 16 v); both d-half waves compute (cheap)
    f32x4 hs0, hs1, hs2;
    {
        f32x4 zv = {0.f,0.f,0.f,0.f};
        f16x8 b0 = *(const f16x8*)(et + (0*16 + r)*64 + g*8);
        f16x8 b1 = *(const f16x8*)(et + (0*16 + r)*64 + 32 + g*8);
        hs0 = __builtin_amdgcn_mfma_f32_16x16x32_f16(a0, b0, zv, 0,0,0);
        hs0 = __builtin_amdgcn_mfma_f32_16x16x32_f16(a1, b1, hs0, 0,0,0);
        b0 = *(const f16x8*)(et + (1*16 + r)*64 + g*8);
        b1 = *(const f16x8*)(et + (1*16 + r)*64 + 32 + g*8);
        hs1 = __builtin_amdgcn_mfma_f32_16x16x32_f16(a0, b0, zv, 0,0,0);
        hs1 = __builtin_amdgcn_mfma_f32_16x16x32_f16(a1, b1, hs1, 0,0,0);
        b0 = *(const f16x8*)(et + (2*16 + r)*64 + g*8);
        b1 = *(const f16x8*)(et + (2*16 + r)*64 + 32 + g*8);
        hs2 = __builtin_amdgcn_mfma_f32_16x16x32_f16(a0, b0, zv, 0,0,0);
        hs2 = __builtin_amdgcn_mfma_f32_16x16x32_f16(a1, b1, hs2, 0,0,0);
    }
    // S[s] = sum_v Ex' * HS ; butterfly over 16 v-cols
    float Sp[4];
    #pragma unroll
    for (int reg = 0; reg < 4; ++reg) {
        Sp[reg] = (float)Exs[(rowD+reg)*56 +  0 + r] * hs0[reg]
                + (float)Exs[(rowD+reg)*56 + 16 + r] * hs1[reg]
                + (float)Exs[(rowD+reg)*56 + 32 + r] * hs2[reg];
    }
    #pragma unroll
    for (int m = 1; m <= 8; m <<= 1) {
        #pragma unroll
        for (int reg = 0; reg < 4; ++reg)
            Sp[reg] += __shfl_xor(Sp[reg], m, 64);
    }

    #define STAGE(BUF, TT) { \
        const _Float16* src_ = vb + (size_t)(TT)*8192 + mw*2048 + lane*8; \
        _Float16* dst_ = Vt + (BUF)*8192 + mw*2048; \
        __builtin_amdgcn_global_load_lds(src_,        dst_,        16, 0, 0); \
        __builtin_amdgcn_global_load_lds(src_ + 512,  dst_ + 512,  16, 0, 0); \
        __builtin_amdgcn_global_load_lds(src_ + 1024, dst_ + 1024, 16, 0, 0); \
        __builtin_amdgcn_global_load_lds(src_ + 1536, dst_ + 1536, 16, 0, 0); }

    f32x4 oacc = {0.f,0.f,0.f,0.f};
    const int sw0 = (g ^ (r&7))*8;
    const int sw1 = ((g+4) ^ (r&7))*8;
    int buf = 0;
    STAGE(0, 0);
    __syncthreads();
    #pragma unroll 1
    for (int tt = 0; tt < 12; ++tt) {
        if (tt < 11) STAGE(buf^1, tt+1);
        const _Float16* VB = Vt + buf*8192;
        const int v0 = tt*4;
        f16x4 exh0 = *(const f16x4*)(Exs + (rowD+0)*56 + v0);
        f16x4 exh1 = *(const f16x4*)(Exs + (rowD+1)*56 + v0);
        f16x4 exh2 = *(const f16x4*)(Exs + (rowD+2)*56 + v0);
        f16x4 exh3 = *(const f16x4*)(Exs + (rowD+3)*56 + v0);
        #pragma unroll
        for (int vl = 0; vl < 4; ++vl) {
            const int row = vl*32 + dh*16 + r;
            f16x8 b0 = *(const f16x8*)(VB + row*64 + sw0);
            f16x8 b1 = *(const f16x8*)(VB + row*64 + sw1);
            f32x4 hz = {0.f,0.f,0.f,0.f};
            hz = __builtin_amdgcn_mfma_f32_16x16x32_f16(a0, b0, hz, 0,0,0);
            hz = __builtin_amdgcn_mfma_f32_16x16x32_f16(a1, b1, hz, 0,0,0);
            oacc[0] += (float)exh0[vl]*hz[0];
            oacc[1] += (float)exh1[vl]*hz[1];
            oacc[2] += (float)exh2[vl]*hz[2];
            oacc[3] += (float)exh3[vl]*hz[3];
        }
        __syncthreads();
        buf ^= 1;
    }

    #pragma unroll
    for (int reg = 0; reg < 4; ++reg) {
        float inv = 1.0f / fmaxf(Sp[reg], 1e-30f);
        size_t base = (size_t)(n*LL + s0 + rowD + reg)*CC + i*32;
        ao[base + dh*16 + r] = oacc[reg] * inv;
    }
}

// ---------------- MFMA proj GEMM: Wp(256x256) @ ao^T -> po fp16 ---------------
__global__ __launch_bounds__(256) void k_gemm_proj(const float* __restrict__ Wp,
                                                   const float* __restrict__ ao,
                                                   _Float16* __restrict__ po) {
    const int n  = blockIdx.z;
    const int m0 = blockIdx.y * 64;
    const int j0 = blockIdx.x * 64;
    const int t = threadIdx.x;
    const int lane = t & 63, mw = t >> 6;
    __shared__ alignas(16) _Float16 As[64*256];
    __shared__ alignas(16) _Float16 Bs[64*256];

    #pragma unroll
    for (int l = 0; l < 8; ++l) {
        int idx = t + 256*l;
        int m = idx >> 5, j = idx & 31;
        const float* srcA = Wp + (size_t)(m0 + m)*CC + j*8;
        float4 a0v = *(const float4*)srcA;
        float4 a1v = *(const float4*)(srcA + 4);
        f16x8 ha;
        ha[0]=(_Float16)a0v.x; ha[1]=(_Float16)a0v.y;
        ha[2]=(_Float16)a0v.z; ha[3]=(_Float16)a0v.w;
        ha[4]=(_Float16)a1v.x; ha[5]=(_Float16)a1v.y;
        ha[6]=(_Float16)a1v.z; ha[7]=(_Float16)a1v.w;
        *(f16x8*)(As + m*256 + ((j ^ (m&7))*8)) = ha;
        const float* srcB = ao + (size_t)(n*LL + j0 + m)*CC + j*8;
        float4 b0v = *(const float4*)srcB;
        float4 b1v = *(const float4*)(srcB + 4);
        f16x8 hb;
        hb[0]=(_Float16)b0v.x; hb[1]=(_Float16)b0v.y;
        hb[2]=(_Float16)b0v.z; hb[3]=(_Float16)b0v.w;
        hb[4]=(_Float16)b1v.x; hb[5]=(_Float16)b1v.y;
        hb[6]=(_Float16)b1v.z; hb[7]=(_Float16)b1v.w;
        *(f16x8*)(Bs + m*256 + ((j ^ (m&7))*8)) = hb;
    }
    __syncthreads();

    const int r = lane & 15, g = lane >> 4;
    f16x8 af[8];
    #pragma unroll
    for (int kk = 0; kk < 8; ++kk)
        af[kk] = *(const f16x8*)(As + (mw*16 + r)*256 + (((kk*4+g) ^ (r&7))*8));
    f32x4 acc0 = {}, acc1 = {}, acc2 = {}, acc3 = {};
    #pragma unroll
    for (int kk = 0; kk < 8; ++kk) {
        f16x8 b0 = *(const f16x8*)(Bs + (0*16 + r)*256 + (((kk*4+g) ^ (r&7))*8));
        f16x8 b1 = *(const f16x8*)(Bs + (1*16 + r)*256 + (((kk*4+g) ^ (r&7))*8));
        f16x8 b2 = *(const f16x8*)(Bs + (2*16 + r)*256 + (((kk*4+g) ^ (r&7))*8));
        f16x8 b3 = *(const f16x8*)(Bs + (3*16 + r)*256 + (((kk*4+g) ^ (r&7))*8));
        acc0 = __builtin_amdgcn_mfma_f32_16x16x32_f16(af[kk], b0, acc0, 0,0,0);
        acc1 = __builtin_amdgcn_mfma_f32_16x16x32_f16(af[kk], b1, acc1, 0,0,0);
        acc2 = __builtin_amdgcn_mfma_f32_16x16x32_f16(af[kk], b2, acc2, 0,0,0);
        acc3 = __builtin_amdgcn_mfma_f32_16x16x32_f16(af[kk], b3, acc3, 0,0,0);
    }

    const int rowD = mw*16 + g*4;
    #pragma unroll
    for (int nf = 0; nf < 4; ++nf) {
        const f32x4& a = (nf==0)?acc0:(nf==1)?acc1:(nf==2)?acc2:acc3;
        int token = j0 + nf*16 + r;
        #pragma unroll
        for (int reg = 0; reg < 4; ++reg) {
            int row = m0 + rowD + reg;
            po[(size_t)(n*CC + row)*LL + token] = (_Float16)a[reg];
        }
    }
}

// ---------------- bilinear x2 upsample + bias + gamma + residual ----------------
__global__ void k_final(const float* __restrict__ x, const _Float16* __restrict__ po,
                        const float* __restrict__ bproj, const float* __restrict__ gammap,
                        float* __restrict__ out) {
    int idx = blockIdx.x*256 + threadIdx.x;
    if (idx >= NB*CC*96*96) return;
    int X = idx % 96, Y = (idx/96) % 96, o = (idx/(96*96)) % CC, n = idx/(96*96*CC);
    float gamma = gammap[0];
    float yf = Y*0.5f - 0.25f, xf = X*0.5f - 0.25f;
    float y0f = floorf(yf), x0f = floorf(xf);
    float tyy = yf - y0f, txx = xf - x0f;
    int y0 = (int)y0f, x0 = (int)x0f;
    int iy0 = max(y0,0), iy1 = min(y0+1,GG-1);
    int ix0 = max(x0,0), ix1 = min(x0+1,GG-1);
    const _Float16* pp = po + (size_t)(n*CC + o)*LL;
    float v00 = (float)pp[iy0*GG+ix0], v01 = (float)pp[iy0*GG+ix1];
    float v10 = (float)pp[iy1*GG+ix0], v11 = (float)pp[iy1*GG+ix1];
    float vy0 = v00 + txx*(v01-v00);
    float vy1 = v10 + txx*(v11-v10);
    float bil = vy0 + tyy*(vy1-vy0);
    out[idx] = gamma*(bil + bproj[o]) + x[idx];
}

extern "C" void kernel_launch(void* const* d_in, const int* in_sizes, int n_in,
                              void* d_out, int out_size, void* d_ws, size_t ws_size,
                              hipStream_t stream) {
    const float* x   = (const float*)d_in[0];
    const float* Wq  = (const float*)d_in[1];
    const float* Wk  = (const float*)d_in[2];
    const float* Wv  = (const float*)d_in[3];
    const float* Wgx = (const float*)d_in[4];
    const float* Wgy = (const float*)d_in[5];
    const float* ab  = (const float*)d_in[6];
    const float* Wp  = (const float*)d_in[7];
    const float* bp  = (const float*)d_in[8];
    const float* gm  = (const float*)d_in[9];
    float* ws = (float*)d_ws;
    _Float16* vbT = (_Float16*)(ws + OFF_VBT);
    _Float16* ebT = (_Float16*)(ws + OFF_EBT);
    float* qbp = ws + OFF_QB;
    _Float16* vtb = (_Float16*)(ws + OFF_VT);
    float* aop = ws + OFF_AO;
    _Float16* xh = (_Float16*)(ws + OFF_XH);   // aliases ao (dead until attn)
    float* ebp = ws + OFF_EB;
    float* ptxp= ws + OFF_PTX;
    float* ptyp= ws + OFF_PTY;
    float* wbp = ws + OFF_WB;
    _Float16* pop = (_Float16*)(ws + OFF_PO);  // fp16, aliases qb
    float* out = (float*)d_out;

    k_xin<<<dim3(LL/64, CC/64, NB), 256, 0, stream>>>(x, xh);
    k_prep<<<dim3(PTAB_N, 3), 256, 0, stream>>>(Wgx, Wgy, Wk, ab, ptxp, ptyp, wbp);
    k_gemm_qv<<<dim3(LL/64, 9, NB), 256, 0, stream>>>(Wq, Wv, wbp, xh, qbp, vtb, ebp);
    k_vtr<<<dim3(NB*HEADS, 6), 256, 0, stream>>>(vtb, ebp, vbT, ebT);
    k_attn<<<dim3(LL/32, NB*HEADS), 256, 0, stream>>>(qbp, vbT, ebT, ptxp, ptyp, aop);
    k_gemm_proj<<<dim3(LL/64, 4, NB), 256, 0, stream>>>(Wp, aop, pop);
    k_final<<<(NB*CC*96*96 + 255)/256, 256, 0, stream>>>(x, pop, bp, gm, out);
}

// Round 22
// 81.777 us; speedup vs baseline: 1.0610x; 1.0610x over previous
//
#include <hip/hip_runtime.h>
#include <math.h>

#define CC 256
#define HEADS 8
#define DD 32
#define GG 48
#define LL (GG*GG)      // 2304
#define NB 2
#define PTAB_N 95

typedef float f32x4 __attribute__((ext_vector_type(4)));
typedef _Float16 f16x8 __attribute__((ext_vector_type(8)));
typedef _Float16 f16x4 __attribute__((ext_vector_type(4)));

// workspace layout (floats).
// vbT/ebT live in the old xs region. xh aliases ao (dead before attn writes ao).
// po (fp16) aliases qb (qb dead after attn).
#define OFF_XS   0
#define SZ_XS    (NB*CC*LL)           // 1,179,648
#define OFF_VBT  OFF_XS               // 786,432 floats (fp16 x 1,572,864)
#define OFF_EBT  (OFF_XS + 786432)    // 24,576 floats (fp16 x 49,152)
#define OFF_QB   (OFF_XS + SZ_XS)
#define SZ_QB    (NB*LL*CC)           // 1,179,648
#define OFF_PO   OFF_QB
#define OFF_VT   (OFF_QB + SZ_QB)
#define SZ_VT_F  (NB*CC*LL/2)         // vtb fp16, 589,824 floats
#define OFF_AO   (OFF_VT + SZ_VT_F)
#define OFF_XH   OFF_AO               // xh fp16 aliases ao
#define SZ_AO    (NB*LL*CC)
#define OFF_EB   (OFF_AO + SZ_AO)
#define SZ_EB    (NB*HEADS*LL)
#define OFF_PTX  (OFF_EB + SZ_EB)
#define SZ_PT    (PTAB_N*CC)
#define OFF_PTY  (OFF_PTX + SZ_PT)
#define OFF_WB   (OFF_PTY + SZ_PT)

// ---------------- fused extract+convert: x (strided) -> xh fp16 swizzled ------
__global__ void k_xin(const float* __restrict__ x, _Float16* __restrict__ xh) {
    const int n = blockIdx.z, c0 = blockIdx.y*64, s0 = blockIdx.x*64;
    const int t = threadIdx.x;
    __shared__ _Float16 ldt[64*72];   // [s][c], row stride 72
    #pragma unroll
    for (int l = 0; l < 4; ++l) {
        int idx = t + 256*l;          // 0..1023
        int cl = idx >> 4, s4 = idx & 15;
        const float* xb = x + (size_t)(n*CC + c0+cl)*96*96;
        #pragma unroll
        for (int e = 0; e < 4; ++e) {
            int s = s0 + s4*4 + e;
            int h = s / GG, w = s % GG;
            ldt[(s4*4+e)*72 + cl] = (_Float16)xb[(2*h)*96 + 2*w];
        }
    }
    __syncthreads();
    #pragma unroll
    for (int l = 0; l < 2; ++l) {
        int idx = t + 256*l;          // 0..511
        int sl = idx >> 3, jg = idx & 7;
        f16x8 o = *(const f16x8*)(ldt + sl*72 + jg*8);
        int s = s0 + sl;
        int p = ((c0 >> 3) + jg) ^ (s & 7);
        *(f16x8*)(xh + (size_t)(n*LL + s)*CC + p*8) = o;
    }
}

// ---------------- merged prep: ptab (y=0,1) + wb (y=2, blocks 0..7) -----------
__global__ void k_prep(const float* __restrict__ Wgx, const float* __restrict__ Wgy,
                       const float* __restrict__ Wk, const float* __restrict__ ab,
                       float* __restrict__ ptx, float* __restrict__ pty,
                       float* __restrict__ wb) {
    const int which = blockIdx.y;
    const int t = threadIdx.x;
    if (which == 2) {
        int i = blockIdx.x;
        if (i < HEADS) {
            float acc = 0.f;
            for (int d = 0; d < DD; ++d) acc += ab[i*DD+d] * Wk[(i*DD+d)*CC + t];
            wb[i*CC + t] = acc;
        }
        return;
    }
    __shared__ float emb[128];
    int ddv = blockIdx.x;
    float diff = 2.0f * (float)(ddv - 47);
    if (t < 64) {
        float dim = powf(1000.0f, (float)t / 64.0f);
        float ang = diff / dim;
        emb[t]      = sinf(ang);
        emb[t + 64] = cosf(ang);
    }
    __syncthreads();
    const float* Wg = which ? Wgy : Wgx;
    float* pt = which ? pty : ptx;
    float acc = 0.f;
    #pragma unroll 8
    for (int e = 0; e < 128; ++e) acc += emb[e] * Wg[t*128 + e];
    pt[ddv*CC + t] = acc * 0.70710678118654752f;
}

// ---------------- MFMA GEMM: A=[Wq;Wv;wb;0] (576x256) @ xh^T -> qb/vtb/ebx ----
__global__ __launch_bounds__(256) void k_gemm_qv(const float* __restrict__ Wq,
                                                 const float* __restrict__ Wv,
                                                 const float* __restrict__ wb,
                                                 const _Float16* __restrict__ xh,
                                                 float* __restrict__ qb,
                                                 _Float16* __restrict__ vtb,
                                                 float* __restrict__ ebx) {
    const int n  = blockIdx.z;
    const int my = blockIdx.y;           // 0..8: m0 = my*64
    const int j0 = blockIdx.x * 64;      // token tile
    const int t = threadIdx.x;
    const int lane = t & 63, mw = t >> 6;
    __shared__ alignas(16) _Float16 As[64*256];
    __shared__ alignas(16) _Float16 Bs[64*256];

    #pragma unroll
    for (int l = 0; l < 8; ++l) {
        int idx = t + 256*l;             // 0..2047
        int m = idx >> 5, j = idx & 31;
        int row = my*64 + m;
        f16x8 h = {};
        if (row < 520) {
            const float* src = (row < 256) ? (Wq + (size_t)row*CC + j*8)
                             : (row < 512) ? (Wv + (size_t)(row-256)*CC + j*8)
                                           : (wb + (size_t)(row-512)*CC + j*8);
            float4 v0 = *(const float4*)(src);
            float4 v1 = *(const float4*)(src + 4);
            h[0]=(_Float16)v0.x; h[1]=(_Float16)v0.y;
            h[2]=(_Float16)v0.z; h[3]=(_Float16)v0.w;
            h[4]=(_Float16)v1.x; h[5]=(_Float16)v1.y;
            h[6]=(_Float16)v1.z; h[7]=(_Float16)v1.w;
        }
        *(f16x8*)(As + m*256 + ((j ^ (m&7))*8)) = h;
    }
    {
        const _Float16* src = xh + (size_t)(n*LL + j0)*CC + mw*4096 + lane*8;
        _Float16* dst = Bs + mw*4096;
        #pragma unroll
        for (int c = 0; c < 8; ++c)
            __builtin_amdgcn_global_load_lds(src + c*512, dst + c*512, 16, 0, 0);
    }
    __syncthreads();

    const int r = lane & 15, g = lane >> 4;
    f16x8 af[8];
    #pragma unroll
    for (int kk = 0; kk < 8; ++kk)
        af[kk] = *(const f16x8*)(As + (mw*16 + r)*256 + (((kk*4+g) ^ (r&7))*8));
    f32x4 acc0 = {}, acc1 = {}, acc2 = {}, acc3 = {};
    #pragma unroll
    for (int kk = 0; kk < 8; ++kk) {
        f16x8 b0 = *(const f16x8*)(Bs + (0*16 + r)*256 + (((kk*4+g) ^ (r&7))*8));
        f16x8 b1 = *(const f16x8*)(Bs + (1*16 + r)*256 + (((kk*4+g) ^ (r&7))*8));
        f16x8 b2 = *(const f16x8*)(Bs + (2*16 + r)*256 + (((kk*4+g) ^ (r&7))*8));
        f16x8 b3 = *(const f16x8*)(Bs + (3*16 + r)*256 + (((kk*4+g) ^ (r&7))*8));
        acc0 = __builtin_amdgcn_mfma_f32_16x16x32_f16(af[kk], b0, acc0, 0,0,0);
        acc1 = __builtin_amdgcn_mfma_f32_16x16x32_f16(af[kk], b1, acc1, 0,0,0);
        acc2 = __builtin_amdgcn_mfma_f32_16x16x32_f16(af[kk], b2, acc2, 0,0,0);
        acc3 = __builtin_amdgcn_mfma_f32_16x16x32_f16(af[kk], b3, acc3, 0,0,0);
    }

    const int rowD = mw*16 + g*4;
    #pragma unroll
    for (int nf = 0; nf < 4; ++nf) {
        const f32x4& a = (nf==0)?acc0:(nf==1)?acc1:(nf==2)?acc2:acc3;
        int token = j0 + nf*16 + r;
        #pragma unroll
        for (int reg = 0; reg < 4; ++reg) {
            int row = my*64 + rowD + reg;
            float v = a[reg];
            if (my < 4) {
                qb[(size_t)(n*LL + token)*CC + row] = v;
            } else if (my < 8) {
                vtb[(size_t)(n*CC + row - 256)*LL + token] = (_Float16)v;
            } else {
                int i = row - 512;
                if (i < 8) ebx[(size_t)(n*HEADS + i)*LL + token] = __expf(v);
            }
        }
    }
}

// ---------------- transpose V to u-contiguous, fold eb, XOR-swizzled ----------
__global__ void k_vtr(const _Float16* __restrict__ vtb, const float* __restrict__ ebx,
                      _Float16* __restrict__ vbT, _Float16* __restrict__ ebT) {
    const int ni = blockIdx.x;
    const int pair = blockIdx.y*256 + threadIdx.x;   // [0,1536)
    const int v = pair >> 5, d = pair & 31;
    const int sw = d & 7;
    const _Float16* vsrc = vtb + (size_t)(ni*32 + d)*LL;
    const float*  ebs  = ebx + (size_t)ni*LL;
    _Float16* dst = vbT + (size_t)ni*98304 + (size_t)(v*32 + d)*64;
    f16x8 z = {};
    #pragma unroll
    for (int c = 0; c < 6; ++c) {
        f16x8 o;
        #pragma unroll
        for (int e = 0; e < 8; ++e) {
            int u = c*8 + e;
            o[e] = (_Float16)((float)vsrc[u*48 + v] * ebs[u*48 + v]);
        }
        *(f16x8*)(dst + (c ^ sw)*8) = o;
    }
    *(f16x8*)(dst + (6 ^ sw)*8) = z;
    *(f16x8*)(dst + (7 ^ sw)*8) = z;
    if (d == 0) {
        _Float16* ed = ebT + (size_t)ni*3072 + (size_t)v*64;
        #pragma unroll
        for (int c = 0; c < 6; ++c) {
            f16x8 o;
            #pragma unroll
            for (int e = 0; e < 8; ++e)
                o[e] = (_Float16)ebs[(c*8+e)*48 + v];
            *(f16x8*)(ed + c*8) = o;
        }
        *(f16x8*)(ed + 48) = z;
        *(f16x8*)(ed + 56) = z;
    }
}

// ---------------- attention v7 (r17/r19-proven): dbuf gload_lds, fp16 Ey/Ex ---
__global__ __launch_bounds__(256) void k_attn(const float* __restrict__ qb,
                                              const _Float16* __restrict__ vbT,
                                              const _Float16* __restrict__ ebT,
                                              const float* __restrict__ ptx,
                                              const float* __restrict__ pty,
                                              float* __restrict__ ao) {
    const int t = threadIdx.x;
    const int lane = t & 63;
    const int mw = t >> 6;
    const int ni = blockIdx.y;
    const int n = ni >> 3, i = ni & 7;
    const int s0 = blockIdx.x * 64;

    // overlay pool: phase1 {qs 8KB, pts 15.2KB} / main {Vt dbuf 2x16KB}
    __shared__ alignas(16) char smpool[32768];
    float*    qs  = (float*)smpool;                 // [2048]
    _Float16* pts = (_Float16*)(smpool + 8192);     // [2][95][40]
    _Float16* Vt  = (_Float16*)smpool;              // [2][8192]
    __shared__ alignas(16) _Float16 Exs[64*56];     // exp(ex-mex) fp16, stride 56
    __shared__ alignas(16) _Float16 Eys[64*72];     // exp(ey-mey) fp16, u-pad 64

    // phase 0: stage Q tile + fp16 head-slices of pos tables
    #pragma unroll
    for (int l = 0; l < 2; ++l) {
        int f = t + 256*l;
        int r4 = f >> 3, dq = f & 7;
        float4 v4 = *(const float4*)(qb + (size_t)(n*LL + s0 + r4)*CC + i*32 + dq*4);
        *(float4*)(&qs[r4*32 + dq*4]) = v4;
    }
    for (int idx = t; idx < 2*PTAB_N*8; idx += 256) {
        int which = idx / (PTAB_N*8);
        int rem = idx % (PTAB_N*8);
        int ddv = rem >> 3, f4 = rem & 7;
        const float* src = (which ? ptx : pty) + (size_t)ddv*CC + i*32 + f4*4;
        float4 v = *(const float4*)src;
        f16x4 hh;
        hh[0]=(_Float16)v.x; hh[1]=(_Float16)v.y;
        hh[2]=(_Float16)v.z; hh[3]=(_Float16)v.w;
        *(f16x4*)(pts + which*(PTAB_N*40) + ddv*40 + f4*4) = hh;
    }
    __syncthreads();

    // phase 1: one q-row per thread-quad; raw ey/ex in registers; quad max
    {
        const int rr = t >> 2, pp = t & 3;
        const int s = s0 + rr, h = s / GG, w = s % GG;
        float4 qreg[8];
        #pragma unroll
        for (int d4 = 0; d4 < 8; ++d4) qreg[d4] = *(const float4*)(qs + rr*32 + d4*4);
        float eyv[12], exv[12];
        float mey = -1e30f, mex = -1e30f;
        #pragma unroll
        for (int k = 0; k < 24; ++k) {
            int j = pp + 4*k;
            const _Float16* tp;
            if (k < 12) tp = pts + (h - j + 47)*40;
            else        tp = pts + PTAB_N*40 + (w - (j-48) + 47)*40;
            float acc = 0.f;
            #pragma unroll
            for (int d8 = 0; d8 < 4; ++d8) {
                f16x8 b = *(const f16x8*)(tp + d8*8);
                float4 a1v = qreg[2*d8], a2v = qreg[2*d8+1];
                acc += a1v.x*(float)b[0] + a1v.y*(float)b[1]
                     + a1v.z*(float)b[2] + a1v.w*(float)b[3]
                     + a2v.x*(float)b[4] + a2v.y*(float)b[5]
                     + a2v.z*(float)b[6] + a2v.w*(float)b[7];
            }
            if (k < 12) { eyv[k] = acc;    mey = fmaxf(mey, acc); }
            else        { exv[k-12] = acc; mex = fmaxf(mex, acc); }
        }
        mey = fmaxf(mey, __shfl_xor(mey, 1, 64));
        mey = fmaxf(mey, __shfl_xor(mey, 2, 64));
        mex = fmaxf(mex, __shfl_xor(mex, 1, 64));
        mex = fmaxf(mex, __shfl_xor(mex, 2, 64));
        #pragma unroll
        for (int k = 0; k < 12; ++k) {
            Eys[rr*72 + pp + 4*k] = (_Float16)__expf(eyv[k] - mey);
            Exs[rr*56 + pp + 4*k] = (_Float16)__expf(exv[k] - mex);
        }
    }
    // zero-pad Ey u 48..63
    for (int zi = t; zi < 64*16; zi += 256) {
        int r = zi >> 4, c = zi & 15;
        Eys[r*72 + 48 + c] = (_Float16)0.f;
    }
    __syncthreads();

    const int r = lane & 15, g = lane >> 4;
    const int rowA = mw*16 + r;
    const int rowD = mw*16 + g*4;

    f16x8 a0 = *(const f16x8*)(Eys + rowA*72 + g*8);
    f16x8 a1 = *(const f16x8*)(Eys + rowA*72 + 32 + g*8);

    const _Float16* vb = vbT + (size_t)ni*(48*32*64);
    const _Float16* et = ebT + (size_t)ni*(48*64);

    // HS = Ey' @ ebT  (3 n-frags of 16 v)
    f32x4 hs0, hs1, hs2;
    {
        f32x4 zv = {0.f,0.f,0.f,0.f};
        f16x8 b0 = *(const f16x8*)(et + (0*16 + r)*64 + g*8);
        f16x8 b1 = *(const f16x8*)(et + (0*16 + r)*64 + 32 + g*8);
        hs0 = __builtin_amdgcn_mfma_f32_16x16x32_f16(a0, b0, zv, 0,0,0);
        hs0 = __builtin_amdgcn_mfma_f32_16x16x32_f16(a1, b1, hs0, 0,0,0);
        b0 = *(const f16x8*)(et + (1*16 + r)*64 + g*8);
        b1 = *(const f16x8*)(et + (1*16 + r)*64 + 32 + g*8);
        hs1 = __builtin_amdgcn_mfma_f32_16x16x32_f16(a0, b0, zv, 0,0,0);
        hs1 = __builtin_amdgcn_mfma_f32_16x16x32_f16(a1, b1, hs1, 0,0,0);
        b0 = *(const f16x8*)(et + (2*16 + r)*64 + g*8);
        b1 = *(const f16x8*)(et + (2*16 + r)*64 + 32 + g*8);
        hs2 = __builtin_amdgcn_mfma_f32_16x16x32_f16(a0, b0, zv, 0,0,0);
        hs2 = __builtin_amdgcn_mfma_f32_16x16x32_f16(a1, b1, hs2, 0,0,0);
    }
    // S[s] = sum_v Ex' * HS ; butterfly over 16 v-cols
    float Sp[4];
    #pragma unroll
    for (int reg = 0; reg < 4; ++reg) {
        Sp[reg] = (float)Exs[(rowD+reg)*56 +  0 + r] * hs0[reg]
                + (float)Exs[(rowD+reg)*56 + 16 + r] * hs1[reg]
                + (float)Exs[(rowD+reg)*56 + 32 + r] * hs2[reg];
    }
    #pragma unroll
    for (int m = 1; m <= 8; m <<= 1) {
        #pragma unroll
        for (int reg = 0; reg < 4; ++reg)
            Sp[reg] += __shfl_xor(Sp[reg], m, 64);
    }

    #define STAGE(BUF, TT) { \
        const _Float16* src_ = vb + (size_t)(TT)*8192 + mw*2048 + lane*8; \
        _Float16* dst_ = Vt + (BUF)*8192 + mw*2048; \
        __builtin_amdgcn_global_load_lds(src_,        dst_,        16, 0, 0); \
        __builtin_amdgcn_global_load_lds(src_ + 512,  dst_ + 512,  16, 0, 0); \
        __builtin_amdgcn_global_load_lds(src_ + 1024, dst_ + 1024, 16, 0, 0); \
        __builtin_amdgcn_global_load_lds(src_ + 1536, dst_ + 1536, 16, 0, 0); }

    f32x4 oacc0 = {0.f,0.f,0.f,0.f}, oacc1 = {0.f,0.f,0.f,0.f};
    const int sw0 = (g ^ (r&7))*8;
    const int sw1 = ((g+4) ^ (r&7))*8;
    int buf = 0;
    STAGE(0, 0);
    __syncthreads();
    #pragma unroll 1
    for (int tt = 0; tt < 12; ++tt) {
        if (tt < 11) STAGE(buf^1, tt+1);
        const _Float16* VB = Vt + buf*8192;
        const int v0 = tt*4;
        f16x4 exh0 = *(const f16x4*)(Exs + (rowD+0)*56 + v0);
        f16x4 exh1 = *(const f16x4*)(Exs + (rowD+1)*56 + v0);
        f16x4 exh2 = *(const f16x4*)(Exs + (rowD+2)*56 + v0);
        f16x4 exh3 = *(const f16x4*)(Exs + (rowD+3)*56 + v0);
        #pragma unroll
        for (int q = 0; q < 8; ++q) {
            const int vl = q >> 1, dh = q & 1;
            const int row = vl*32 + dh*16 + r;
            f16x8 b0 = *(const f16x8*)(VB + row*64 + sw0);
            f16x8 b1 = *(const f16x8*)(VB + row*64 + sw1);
            float e0 = (float)exh0[vl];
            float e1 = (float)exh1[vl];
            float e2 = (float)exh2[vl];
            float e3 = (float)exh3[vl];
            f32x4 hz = {0.f,0.f,0.f,0.f};
            hz = __builtin_amdgcn_mfma_f32_16x16x32_f16(a0, b0, hz, 0,0,0);
            hz = __builtin_amdgcn_mfma_f32_16x16x32_f16(a1, b1, hz, 0,0,0);
            if (dh == 0) {
                oacc0[0] += e0*hz[0]; oacc0[1] += e1*hz[1];
                oacc0[2] += e2*hz[2]; oacc0[3] += e3*hz[3];
            } else {
                oacc1[0] += e0*hz[0]; oacc1[1] += e1*hz[1];
                oacc1[2] += e2*hz[2]; oacc1[3] += e3*hz[3];
            }
        }
        __syncthreads();
        buf ^= 1;
    }

    #pragma unroll
    for (int reg = 0; reg < 4; ++reg) {
        float inv = 1.0f / fmaxf(Sp[reg], 1e-30f);
        size_t base = (size_t)(n*LL + s0 + rowD + reg)*CC + i*32;
        ao[base + r]      = oacc0[reg] * inv;
        ao[base + 16 + r] = oacc1[reg] * inv;
    }
}

// ---------------- MFMA proj GEMM: Wp(256x256) @ ao^T -> po fp16 ---------------
__global__ __launch_bounds__(256) void k_gemm_proj(const float* __restrict__ Wp,
                                                   const float* __restrict__ ao,
                                                   _Float16* __restrict__ po) {
    const int n  = blockIdx.z;
    const int m0 = blockIdx.y * 64;
    const int j0 = blockIdx.x * 64;
    const int t = threadIdx.x;
    const int lane = t & 63, mw = t >> 6;
    __shared__ alignas(16) _Float16 As[64*256];
    __shared__ alignas(16) _Float16 Bs[64*256];

    #pragma unroll
    for (int l = 0; l < 8; ++l) {
        int idx = t + 256*l;
        int m = idx >> 5, j = idx & 31;
        const float* srcA = Wp + (size_t)(m0 + m)*CC + j*8;
        float4 a0v = *(const float4*)srcA;
        float4 a1v = *(const float4*)(srcA + 4);
        f16x8 ha;
        ha[0]=(_Float16)a0v.x; ha[1]=(_Float16)a0v.y;
        ha[2]=(_Float16)a0v.z; ha[3]=(_Float16)a0v.w;
        ha[4]=(_Float16)a1v.x; ha[5]=(_Float16)a1v.y;
        ha[6]=(_Float16)a1v.z; ha[7]=(_Float16)a1v.w;
        *(f16x8*)(As + m*256 + ((j ^ (m&7))*8)) = ha;
        const float* srcB = ao + (size_t)(n*LL + j0 + m)*CC + j*8;
        float4 b0v = *(const float4*)srcB;
        float4 b1v = *(const float4*)(srcB + 4);
        f16x8 hb;
        hb[0]=(_Float16)b0v.x; hb[1]=(_Float16)b0v.y;
        hb[2]=(_Float16)b0v.z; hb[3]=(_Float16)b0v.w;
        hb[4]=(_Float16)b1v.x; hb[5]=(_Float16)b1v.y;
        hb[6]=(_Float16)b1v.z; hb[7]=(_Float16)b1v.w;
        *(f16x8*)(Bs + m*256 + ((j ^ (m&7))*8)) = hb;
    }
    __syncthreads();

    const int r = lane & 15, g = lane >> 4;
    f16x8 af[8];
    #pragma unroll
    for (int kk = 0; kk < 8; ++kk)
        af[kk] = *(const f16x8*)(As + (mw*16 + r)*256 + (((kk*4+g) ^ (r&7))*8));
    f32x4 acc0 = {}, acc1 = {}, acc2 = {}, acc3 = {};
    #pragma unroll
    for (int kk = 0; kk < 8; ++kk) {
        f16x8 b0 = *(const f16x8*)(Bs + (0*16 + r)*256 + (((kk*4+g) ^ (r&7))*8));
        f16x8 b1 = *(const f16x8*)(Bs + (1*16 + r)*256 + (((kk*4+g) ^ (r&7))*8));
        f16x8 b2 = *(const f16x8*)(Bs + (2*16 + r)*256 + (((kk*4+g) ^ (r&7))*8));
        f16x8 b3 = *(const f16x8*)(Bs + (3*16 + r)*256 + (((kk*4+g) ^ (r&7))*8));
        acc0 = __builtin_amdgcn_mfma_f32_16x16x32_f16(af[kk], b0, acc0, 0,0,0);
        acc1 = __builtin_amdgcn_mfma_f32_16x16x32_f16(af[kk], b1, acc1, 0,0,0);
        acc2 = __builtin_amdgcn_mfma_f32_16x16x32_f16(af[kk], b2, acc2, 0,0,0);
        acc3 = __builtin_amdgcn_mfma_f32_16x16x32_f16(af[kk], b3, acc3, 0,0,0);
    }

    const int rowD = mw*16 + g*4;
    #pragma unroll
    for (int nf = 0; nf < 4; ++nf) {
        const f32x4& a = (nf==0)?acc0:(nf==1)?acc1:(nf==2)?acc2:acc3;
        int token = j0 + nf*16 + r;
        #pragma unroll
        for (int reg = 0; reg < 4; ++reg) {
            int row = m0 + rowD + reg;
            po[(size_t)(n*CC + row)*LL + token] = (_Float16)a[reg];
        }
    }
}

// ---------------- bilinear x2 upsample + bias + gamma + residual ----------------
__global__ void k_final(const float* __restrict__ x, const _Float16* __restrict__ po,
                        const float* __restrict__ bproj, const float* __restrict__ gammap,
                        float* __restrict__ out) {
    int idx = blockIdx.x*256 + threadIdx.x;
    if (idx >= NB*CC*96*96) return;
    int X = idx % 96, Y = (idx/96) % 96, o = (idx/(96*96)) % CC, n = idx/(96*96*CC);
    float gamma = gammap[0];
    float yf = Y*0.5f - 0.25f, xf = X*0.5f - 0.25f;
    float y0f = floorf(yf), x0f = floorf(xf);
    float tyy = yf - y0f, txx = xf - x0f;
    int y0 = (int)y0f, x0 = (int)x0f;
    int iy0 = max(y0,0), iy1 = min(y0+1,GG-1);
    int ix0 = max(x0,0), ix1 = min(x0+1,GG-1);
    const _Float16* pp = po + (size_t)(n*CC + o)*LL;
    float v00 = (float)pp[iy0*GG+ix0], v01 = (float)pp[iy0*GG+ix1];
    float v10 = (float)pp[iy1*GG+ix0], v11 = (float)pp[iy1*GG+ix1];
    float vy0 = v00 + txx*(v01-v00);
    float vy1 = v10 + txx*(v11-v10);
    float bil = vy0 + tyy*(vy1-vy0);
    out[idx] = gamma*(bil + bproj[o]) + x[idx];
}

extern "C" void kernel_launch(void* const* d_in, const int* in_sizes, int n_in,
                              void* d_out, int out_size, void* d_ws, size_t ws_size,
                              hipStream_t stream) {
    const float* x   = (const float*)d_in[0];
    const float* Wq  = (const float*)d_in[1];
    const float* Wk  = (const float*)d_in[2];
    const float* Wv  = (const float*)d_in[3];
    const float* Wgx = (const float*)d_in[4];
    const float* Wgy = (const float*)d_in[5];
    const float* ab  = (const float*)d_in[6];
    const float* Wp  = (const float*)d_in[7];
    const float* bp  = (const float*)d_in[8];
    const float* gm  = (const float*)d_in[9];
    float* ws = (float*)d_ws;
    _Float16* vbT = (_Float16*)(ws + OFF_VBT);
    _Float16* ebT = (_Float16*)(ws + OFF_EBT);
    float* qbp = ws + OFF_QB;
    _Float16* vtb = (_Float16*)(ws + OFF_VT);
    float* aop = ws + OFF_AO;
    _Float16* xh = (_Float16*)(ws + OFF_XH);   // aliases ao (dead until attn)
    float* ebp = ws + OFF_EB;
    float* ptxp= ws + OFF_PTX;
    float* ptyp= ws + OFF_PTY;
    float* wbp = ws + OFF_WB;
    _Float16* pop = (_Float16*)(ws + OFF_PO);  // fp16, aliases qb
    float* out = (float*)d_out;

    k_xin<<<dim3(LL/64, CC/64, NB), 256, 0, stream>>>(x, xh);
    k_prep<<<dim3(PTAB_N, 3), 256, 0, stream>>>(Wgx, Wgy, Wk, ab, ptxp, ptyp, wbp);
    k_gemm_qv<<<dim3(LL/64, 9, NB), 256, 0, stream>>>(Wq, Wv, wbp, xh, qbp, vtb, ebp);
    k_vtr<<<dim3(NB*HEADS, 6), 256, 0, stream>>>(vtb, ebp, vbT, ebT);
    k_attn<<<dim3(LL/64, NB*HEADS), 256, 0, stream>>>(qbp, vbT, ebT, ptxp, ptyp, aop);
    k_gemm_proj<<<dim3(LL/64, 4, NB), 256, 0, stream>>>(Wp, aop, pop);
    k_final<<<(NB*CC*96*96 + 255)/256, 256, 0, stream>>>(x, pop, bp, gm, out);
}

// Round 23
// 81.673 us; speedup vs baseline: 1.0623x; 1.0013x over previous
//
#include <hip/hip_runtime.h>
#include <math.h>

#define CC 256
#define HEADS 8
#define DD 32
#define GG 48
#define LL (GG*GG)      // 2304
#define NB 2
#define PTAB_N 95

typedef float f32x4 __attribute__((ext_vector_type(4)));
typedef _Float16 f16x8 __attribute__((ext_vector_type(8)));
typedef _Float16 f16x4 __attribute__((ext_vector_type(4)));

// workspace layout (floats).
// vbT/ebT live in the old xs region. xh aliases ao (dead before attn writes ao).
// po (fp16) aliases qb (qb dead after attn).
#define OFF_XS   0
#define SZ_XS    (NB*CC*LL)           // 1,179,648
#define OFF_VBT  OFF_XS               // 786,432 floats (fp16 x 1,572,864)
#define OFF_EBT  (OFF_XS + 786432)    // 24,576 floats (fp16 x 49,152)
#define OFF_QB   (OFF_XS + SZ_XS)
#define SZ_QB    (NB*LL*CC)           // 1,179,648
#define OFF_PO   OFF_QB
#define OFF_VT   (OFF_QB + SZ_QB)
#define SZ_VT_F  (NB*CC*LL/2)         // vtb fp16, 589,824 floats
#define OFF_AO   (OFF_VT + SZ_VT_F)
#define OFF_XH   OFF_AO               // xh fp16 aliases ao
#define SZ_AO    (NB*LL*CC)
#define OFF_EB   (OFF_AO + SZ_AO)
#define SZ_EB    (NB*HEADS*LL)
#define OFF_PTX  (OFF_EB + SZ_EB)
#define SZ_PT    (PTAB_N*CC)
#define OFF_PTY  (OFF_PTX + SZ_PT)
#define OFF_WB   (OFF_PTY + SZ_PT)

// ---------------- fused extract+convert: x (strided) -> xh fp16 swizzled ------
__global__ void k_xin(const float* __restrict__ x, _Float16* __restrict__ xh) {
    const int n = blockIdx.z, c0 = blockIdx.y*64, s0 = blockIdx.x*64;
    const int t = threadIdx.x;
    __shared__ _Float16 ldt[64*72];   // [s][c], row stride 72
    #pragma unroll
    for (int l = 0; l < 4; ++l) {
        int idx = t + 256*l;          // 0..1023
        int cl = idx >> 4, s4 = idx & 15;
        const float* xb = x + (size_t)(n*CC + c0+cl)*96*96;
        #pragma unroll
        for (int e = 0; e < 4; ++e) {
            int s = s0 + s4*4 + e;
            int h = s / GG, w = s % GG;
            ldt[(s4*4+e)*72 + cl] = (_Float16)xb[(2*h)*96 + 2*w];
        }
    }
    __syncthreads();
    #pragma unroll
    for (int l = 0; l < 2; ++l) {
        int idx = t + 256*l;          // 0..511
        int sl = idx >> 3, jg = idx & 7;
        f16x8 o = *(const f16x8*)(ldt + sl*72 + jg*8);
        int s = s0 + sl;
        int p = ((c0 >> 3) + jg) ^ (s & 7);
        *(f16x8*)(xh + (size_t)(n*LL + s)*CC + p*8) = o;
    }
}

// ---------------- merged prep: ptab (y=0,1) + wb (y=2, blocks 0..7) -----------
__global__ void k_prep(const float* __restrict__ Wgx, const float* __restrict__ Wgy,
                       const float* __restrict__ Wk, const float* __restrict__ ab,
                       float* __restrict__ ptx, float* __restrict__ pty,
                       float* __restrict__ wb) {
    const int which = blockIdx.y;
    const int t = threadIdx.x;
    if (which == 2) {
        int i = blockIdx.x;
        if (i < HEADS) {
            float acc = 0.f;
            for (int d = 0; d < DD; ++d) acc += ab[i*DD+d] * Wk[(i*DD+d)*CC + t];
            wb[i*CC + t] = acc;
        }
        return;
    }
    __shared__ float emb[128];
    int ddv = blockIdx.x;
    float diff = 2.0f * (float)(ddv - 47);
    if (t < 64) {
        float dim = powf(1000.0f, (float)t / 64.0f);
        float ang = diff / dim;
        emb[t]      = sinf(ang);
        emb[t + 64] = cosf(ang);
    }
    __syncthreads();
    const float* Wg = which ? Wgy : Wgx;
    float* pt = which ? pty : ptx;
    float acc = 0.f;
    #pragma unroll 8
    for (int e = 0; e < 128; ++e) acc += emb[e] * Wg[t*128 + e];
    pt[ddv*CC + t] = acc * 0.70710678118654752f;
}

// ---------------- MFMA GEMM: A=[Wq;Wv;wb;0] (576x256) @ xh^T -> qb/vtb/ebx ----
__global__ __launch_bounds__(256) void k_gemm_qv(const float* __restrict__ Wq,
                                                 const float* __restrict__ Wv,
                                                 const float* __restrict__ wb,
                                                 const _Float16* __restrict__ xh,
                                                 float* __restrict__ qb,
                                                 _Float16* __restrict__ vtb,
                                                 float* __restrict__ ebx) {
    const int n  = blockIdx.z;
    const int my = blockIdx.y;           // 0..8: m0 = my*64
    const int j0 = blockIdx.x * 64;      // token tile
    const int t = threadIdx.x;
    const int lane = t & 63, mw = t >> 6;
    __shared__ alignas(16) _Float16 As[64*256];
    __shared__ alignas(16) _Float16 Bs[64*256];

    #pragma unroll
    for (int l = 0; l < 8; ++l) {
        int idx = t + 256*l;             // 0..2047
        int m = idx >> 5, j = idx & 31;
        int row = my*64 + m;
        f16x8 h = {};
        if (row < 520) {
            const float* src = (row < 256) ? (Wq + (size_t)row*CC + j*8)
                             : (row < 512) ? (Wv + (size_t)(row-256)*CC + j*8)
                                           : (wb + (size_t)(row-512)*CC + j*8);
            float4 v0 = *(const float4*)(src);
            float4 v1 = *(const float4*)(src + 4);
            h[0]=(_Float16)v0.x; h[1]=(_Float16)v0.y;
            h[2]=(_Float16)v0.z; h[3]=(_Float16)v0.w;
            h[4]=(_Float16)v1.x; h[5]=(_Float16)v1.y;
            h[6]=(_Float16)v1.z; h[7]=(_Float16)v1.w;
        }
        *(f16x8*)(As + m*256 + ((j ^ (m&7))*8)) = h;
    }
    {
        const _Float16* src = xh + (size_t)(n*LL + j0)*CC + mw*4096 + lane*8;
        _Float16* dst = Bs + mw*4096;
        #pragma unroll
        for (int c = 0; c < 8; ++c)
            __builtin_amdgcn_global_load_lds(src + c*512, dst + c*512, 16, 0, 0);
    }
    __syncthreads();

    const int r = lane & 15, g = lane >> 4;
    f16x8 af[8];
    #pragma unroll
    for (int kk = 0; kk < 8; ++kk)
        af[kk] = *(const f16x8*)(As + (mw*16 + r)*256 + (((kk*4+g) ^ (r&7))*8));
    f32x4 acc0 = {}, acc1 = {}, acc2 = {}, acc3 = {};
    #pragma unroll
    for (int kk = 0; kk < 8; ++kk) {
        f16x8 b0 = *(const f16x8*)(Bs + (0*16 + r)*256 + (((kk*4+g) ^ (r&7))*8));
        f16x8 b1 = *(const f16x8*)(Bs + (1*16 + r)*256 + (((kk*4+g) ^ (r&7))*8));
        f16x8 b2 = *(const f16x8*)(Bs + (2*16 + r)*256 + (((kk*4+g) ^ (r&7))*8));
        f16x8 b3 = *(const f16x8*)(Bs + (3*16 + r)*256 + (((kk*4+g) ^ (r&7))*8));
        acc0 = __builtin_amdgcn_mfma_f32_16x16x32_f16(af[kk], b0, acc0, 0,0,0);
        acc1 = __builtin_amdgcn_mfma_f32_16x16x32_f16(af[kk], b1, acc1, 0,0,0);
        acc2 = __builtin_amdgcn_mfma_f32_16x16x32_f16(af[kk], b2, acc2, 0,0,0);
        acc3 = __builtin_amdgcn_mfma_f32_16x16x32_f16(af[kk], b3, acc3, 0,0,0);
    }

    const int rowD = mw*16 + g*4;
    #pragma unroll
    for (int nf = 0; nf < 4; ++nf) {
        const f32x4& a = (nf==0)?acc0:(nf==1)?acc1:(nf==2)?acc2:acc3;
        int token = j0 + nf*16 + r;
        #pragma unroll
        for (int reg = 0; reg < 4; ++reg) {
            int row = my*64 + rowD + reg;
            float v = a[reg];
            if (my < 4) {
                qb[(size_t)(n*LL + token)*CC + row] = v;
            } else if (my < 8) {
                vtb[(size_t)(n*CC + row - 256)*LL + token] = (_Float16)v;
            } else {
                int i = row - 512;
                if (i < 8) ebx[(size_t)(n*HEADS + i)*LL + token] = __expf(v);
            }
        }
    }
}

// ---------------- transpose V to u-contiguous, fold eb, XOR-swizzled ----------
__global__ void k_vtr(const _Float16* __restrict__ vtb, const float* __restrict__ ebx,
                      _Float16* __restrict__ vbT, _Float16* __restrict__ ebT) {
    const int ni = blockIdx.x;
    const int pair = blockIdx.y*256 + threadIdx.x;   // [0,1536)
    const int v = pair >> 5, d = pair & 31;
    const int sw = d & 7;
    const _Float16* vsrc = vtb + (size_t)(ni*32 + d)*LL;
    const float*  ebs  = ebx + (size_t)ni*LL;
    _Float16* dst = vbT + (size_t)ni*98304 + (size_t)(v*32 + d)*64;
    f16x8 z = {};
    #pragma unroll
    for (int c = 0; c < 6; ++c) {
        f16x8 o;
        #pragma unroll
        for (int e = 0; e < 8; ++e) {
            int u = c*8 + e;
            o[e] = (_Float16)((float)vsrc[u*48 + v] * ebs[u*48 + v]);
        }
        *(f16x8*)(dst + (c ^ sw)*8) = o;
    }
    *(f16x8*)(dst + (6 ^ sw)*8) = z;
    *(f16x8*)(dst + (7 ^ sw)*8) = z;
    if (d == 0) {
        _Float16* ed = ebT + (size_t)ni*3072 + (size_t)v*64;
        #pragma unroll
        for (int c = 0; c < 6; ++c) {
            f16x8 o;
            #pragma unroll
            for (int e = 0; e < 8; ++e)
                o[e] = (_Float16)ebs[(c*8+e)*48 + v];
            *(f16x8*)(ed + c*8) = o;
        }
        *(f16x8*)(ed + 48) = z;
        *(f16x8*)(ed + 56) = z;
    }
}

// ---------------- attention v7 (r17/r19-proven): dbuf gload_lds, fp16 Ey/Ex ---
__global__ __launch_bounds__(256) void k_attn(const float* __restrict__ qb,
                                              const _Float16* __restrict__ vbT,
                                              const _Float16* __restrict__ ebT,
                                              const float* __restrict__ ptx,
                                              const float* __restrict__ pty,
                                              float* __restrict__ ao) {
    const int t = threadIdx.x;
    const int lane = t & 63;
    const int mw = t >> 6;
    const int ni = blockIdx.y;
    const int n = ni >> 3, i = ni & 7;
    const int s0 = blockIdx.x * 64;

    // overlay pool: phase1 {qs 8KB, pts 15.2KB} / main {Vt dbuf 2x16KB}
    __shared__ alignas(16) char smpool[32768];
    float*    qs  = (float*)smpool;                 // [2048]
    _Float16* pts = (_Float16*)(smpool + 8192);     // [2][95][40]
    _Float16* Vt  = (_Float16*)smpool;              // [2][8192]
    __shared__ alignas(16) _Float16 Exs[64*56];     // exp(ex-mex) fp16, stride 56
    __shared__ alignas(16) _Float16 Eys[64*72];     // exp(ey-mey) fp16, u-pad 64

    // phase 0: stage Q tile + fp16 head-slices of pos tables
    #pragma unroll
    for (int l = 0; l < 2; ++l) {
        int f = t + 256*l;
        int r4 = f >> 3, dq = f & 7;
        float4 v4 = *(const float4*)(qb + (size_t)(n*LL + s0 + r4)*CC + i*32 + dq*4);
        *(float4*)(&qs[r4*32 + dq*4]) = v4;
    }
    for (int idx = t; idx < 2*PTAB_N*8; idx += 256) {
        int which = idx / (PTAB_N*8);
        int rem = idx % (PTAB_N*8);
        int ddv = rem >> 3, f4 = rem & 7;
        const float* src = (which ? ptx : pty) + (size_t)ddv*CC + i*32 + f4*4;
        float4 v = *(const float4*)src;
        f16x4 hh;
        hh[0]=(_Float16)v.x; hh[1]=(_Float16)v.y;
        hh[2]=(_Float16)v.z; hh[3]=(_Float16)v.w;
        *(f16x4*)(pts + which*(PTAB_N*40) + ddv*40 + f4*4) = hh;
    }
    __syncthreads();

    // phase 1: one q-row per thread-quad; raw ey/ex in registers; quad max
    {
        const int rr = t >> 2, pp = t & 3;
        const int s = s0 + rr, h = s / GG, w = s % GG;
        float4 qreg[8];
        #pragma unroll
        for (int d4 = 0; d4 < 8; ++d4) qreg[d4] = *(const float4*)(qs + rr*32 + d4*4);
        float eyv[12], exv[12];
        float mey = -1e30f, mex = -1e30f;
        #pragma unroll
        for (int k = 0; k < 24; ++k) {
            int j = pp + 4*k;
            const _Float16* tp;
            if (k < 12) tp = pts + (h - j + 47)*40;
            else        tp = pts + PTAB_N*40 + (w - (j-48) + 47)*40;
            float acc = 0.f;
            #pragma unroll
            for (int d8 = 0; d8 < 4; ++d8) {
                f16x8 b = *(const f16x8*)(tp + d8*8);
                float4 a1v = qreg[2*d8], a2v = qreg[2*d8+1];
                acc += a1v.x*(float)b[0] + a1v.y*(float)b[1]
                     + a1v.z*(float)b[2] + a1v.w*(float)b[3]
                     + a2v.x*(float)b[4] + a2v.y*(float)b[5]
                     + a2v.z*(float)b[6] + a2v.w*(float)b[7];
            }
            if (k < 12) { eyv[k] = acc;    mey = fmaxf(mey, acc); }
            else        { exv[k-12] = acc; mex = fmaxf(mex, acc); }
        }
        mey = fmaxf(mey, __shfl_xor(mey, 1, 64));
        mey = fmaxf(mey, __shfl_xor(mey, 2, 64));
        mex = fmaxf(mex, __shfl_xor(mex, 1, 64));
        mex = fmaxf(mex, __shfl_xor(mex, 2, 64));
        #pragma unroll
        for (int k = 0; k < 12; ++k) {
            Eys[rr*72 + pp + 4*k] = (_Float16)__expf(eyv[k] - mey);
            Exs[rr*56 + pp + 4*k] = (_Float16)__expf(exv[k] - mex);
        }
    }
    // zero-pad Ey u 48..63
    for (int zi = t; zi < 64*16; zi += 256) {
        int r = zi >> 4, c = zi & 15;
        Eys[r*72 + 48 + c] = (_Float16)0.f;
    }
    __syncthreads();

    const int r = lane & 15, g = lane >> 4;
    const int rowA = mw*16 + r;
    const int rowD = mw*16 + g*4;

    f16x8 a0 = *(const f16x8*)(Eys + rowA*72 + g*8);
    f16x8 a1 = *(const f16x8*)(Eys + rowA*72 + 32 + g*8);

    const _Float16* vb = vbT + (size_t)ni*(48*32*64);
    const _Float16* et = ebT + (size_t)ni*(48*64);

    // HS = Ey' @ ebT  (3 n-frags of 16 v)
    f32x4 hs0, hs1, hs2;
    {
        f32x4 zv = {0.f,0.f,0.f,0.f};
        f16x8 b0 = *(const f16x8*)(et + (0*16 + r)*64 + g*8);
        f16x8 b1 = *(const f16x8*)(et + (0*16 + r)*64 + 32 + g*8);
        hs0 = __builtin_amdgcn_mfma_f32_16x16x32_f16(a0, b0, zv, 0,0,0);
        hs0 = __builtin_amdgcn_mfma_f32_16x16x32_f16(a1, b1, hs0, 0,0,0);
        b0 = *(const f16x8*)(et + (1*16 + r)*64 + g*8);
        b1 = *(const f16x8*)(et + (1*16 + r)*64 + 32 + g*8);
        hs1 = __builtin_amdgcn_mfma_f32_16x16x32_f16(a0, b0, zv, 0,0,0);
        hs1 = __builtin_amdgcn_mfma_f32_16x16x32_f16(a1, b1, hs1, 0,0,0);
        b0 = *(const f16x8*)(et + (2*16 + r)*64 + g*8);
        b1 = *(const f16x8*)(et + (2*16 + r)*64 + 32 + g*8);
        hs2 = __builtin_amdgcn_mfma_f32_16x16x32_f16(a0, b0, zv, 0,0,0);
        hs2 = __builtin_amdgcn_mfma_f32_16x16x32_f16(a1, b1, hs2, 0,0,0);
    }
    // S[s] = sum_v Ex' * HS ; butterfly over 16 v-cols
    float Sp[4];
    #pragma unroll
    for (int reg = 0; reg < 4; ++reg) {
        Sp[reg] = (float)Exs[(rowD+reg)*56 +  0 + r] * hs0[reg]
                + (float)Exs[(rowD+reg)*56 + 16 + r] * hs1[reg]
                + (float)Exs[(rowD+reg)*56 + 32 + r] * hs2[reg];
    }
    #pragma unroll
    for (int m = 1; m <= 8; m <<= 1) {
        #pragma unroll
        for (int reg = 0; reg < 4; ++reg)
            Sp[reg] += __shfl_xor(Sp[reg], m, 64);
    }

    #define STAGE(BUF, TT) { \
        const _Float16* src_ = vb + (size_t)(TT)*8192 + mw*2048 + lane*8; \
        _Float16* dst_ = Vt + (BUF)*8192 + mw*2048; \
        __builtin_amdgcn_global_load_lds(src_,        dst_,        16, 0, 0); \
        __builtin_amdgcn_global_load_lds(src_ + 512,  dst_ + 512,  16, 0, 0); \
        __builtin_amdgcn_global_load_lds(src_ + 1024, dst_ + 1024, 16, 0, 0); \
        __builtin_amdgcn_global_load_lds(src_ + 1536, dst_ + 1536, 16, 0, 0); }

    f32x4 oacc0 = {0.f,0.f,0.f,0.f}, oacc1 = {0.f,0.f,0.f,0.f};
    const int sw0 = (g ^ (r&7))*8;
    const int sw1 = ((g+4) ^ (r&7))*8;
    int buf = 0;
    STAGE(0, 0);
    __syncthreads();
    #pragma unroll 1
    for (int tt = 0; tt < 12; ++tt) {
        if (tt < 11) STAGE(buf^1, tt+1);
        const _Float16* VB = Vt + buf*8192;
        const int v0 = tt*4;
        f16x4 exh0 = *(const f16x4*)(Exs + (rowD+0)*56 + v0);
        f16x4 exh1 = *(const f16x4*)(Exs + (rowD+1)*56 + v0);
        f16x4 exh2 = *(const f16x4*)(Exs + (rowD+2)*56 + v0);
        f16x4 exh3 = *(const f16x4*)(Exs + (rowD+3)*56 + v0);
        #pragma unroll
        for (int q = 0; q < 8; ++q) {
            const int vl = q >> 1, dh = q & 1;
            const int row = vl*32 + dh*16 + r;
            f16x8 b0 = *(const f16x8*)(VB + row*64 + sw0);
            f16x8 b1 = *(const f16x8*)(VB + row*64 + sw1);
            float e0 = (float)exh0[vl];
            float e1 = (float)exh1[vl];
            float e2 = (float)exh2[vl];
            float e3 = (float)exh3[vl];
            f32x4 hz = {0.f,0.f,0.f,0.f};
            hz = __builtin_amdgcn_mfma_f32_16x16x32_f16(a0, b0, hz, 0,0,0);
            hz = __builtin_amdgcn_mfma_f32_16x16x32_f16(a1, b1, hz, 0,0,0);
            if (dh == 0) {
                oacc0[0] += e0*hz[0]; oacc0[1] += e1*hz[1];
                oacc0[2] += e2*hz[2]; oacc0[3] += e3*hz[3];
            } else {
                oacc1[0] += e0*hz[0]; oacc1[1] += e1*hz[1];
                oacc1[2] += e2*hz[2]; oacc1[3] += e3*hz[3];
            }
        }
        __syncthreads();
        buf ^= 1;
    }

    #pragma unroll
    for (int reg = 0; reg < 4; ++reg) {
        float inv = 1.0f / fmaxf(Sp[reg], 1e-30f);
        size_t base = (size_t)(n*LL + s0 + rowD + reg)*CC + i*32;
        ao[base + r]      = oacc0[reg] * inv;
        ao[base + 16 + r] = oacc1[reg] * inv;
    }
}

// ---------------- MFMA proj GEMM: Wp(256x256) @ ao^T -> po fp16 ---------------
__global__ __launch_bounds__(256) void k_gemm_proj(const float* __restrict__ Wp,
                                                   const float* __restrict__ ao,
                                                   _Float16* __restrict__ po) {
    const int n  = blockIdx.z;
    const int m0 = blockIdx.y * 64;
    const int j0 = blockIdx.x * 64;
    const int t = threadIdx.x;
    const int lane = t & 63, mw = t >> 6;
    __shared__ alignas(16) _Float16 As[64*256];
    __shared__ alignas(16) _Float16 Bs[64*256];

    #pragma unroll
    for (int l = 0; l < 8; ++l) {
        int idx = t + 256*l;
        int m = idx >> 5, j = idx & 31;
        const float* srcA = Wp + (size_t)(m0 + m)*CC + j*8;
        float4 a0v = *(const float4*)srcA;
        float4 a1v = *(const float4*)(srcA + 4);
        f16x8 ha;
        ha[0]=(_Float16)a0v.x; ha[1]=(_Float16)a0v.y;
        ha[2]=(_Float16)a0v.z; ha[3]=(_Float16)a0v.w;
        ha[4]=(_Float16)a1v.x; ha[5]=(_Float16)a1v.y;
        ha[6]=(_Float16)a1v.z; ha[7]=(_Float16)a1v.w;
        *(f16x8*)(As + m*256 + ((j ^ (m&7))*8)) = ha;
        const float* srcB = ao + (size_t)(n*LL + j0 + m)*CC + j*8;
        float4 b0v = *(const float4*)srcB;
        float4 b1v = *(const float4*)(srcB + 4);
        f16x8 hb;
        hb[0]=(_Float16)b0v.x; hb[1]=(_Float16)b0v.y;
        hb[2]=(_Float16)b0v.z; hb[3]=(_Float16)b0v.w;
        hb[4]=(_Float16)b1v.x; hb[5]=(_Float16)b1v.y;
        hb[6]=(_Float16)b1v.z; hb[7]=(_Float16)b1v.w;
        *(f16x8*)(Bs + m*256 + ((j ^ (m&7))*8)) = hb;
    }
    __syncthreads();

    const int r = lane & 15, g = lane >> 4;
    f16x8 af[8];
    #pragma unroll
    for (int kk = 0; kk < 8; ++kk)
        af[kk] = *(const f16x8*)(As + (mw*16 + r)*256 + (((kk*4+g) ^ (r&7))*8));
    f32x4 acc0 = {}, acc1 = {}, acc2 = {}, acc3 = {};
    #pragma unroll
    for (int kk = 0; kk < 8; ++kk) {
        f16x8 b0 = *(const f16x8*)(Bs + (0*16 + r)*256 + (((kk*4+g) ^ (r&7))*8));
        f16x8 b1 = *(const f16x8*)(Bs + (1*16 + r)*256 + (((kk*4+g) ^ (r&7))*8));
        f16x8 b2 = *(const f16x8*)(Bs + (2*16 + r)*256 + (((kk*4+g) ^ (r&7))*8));
        f16x8 b3 = *(const f16x8*)(Bs + (3*16 + r)*256 + (((kk*4+g) ^ (r&7))*8));
        acc0 = __builtin_amdgcn_mfma_f32_16x16x32_f16(af[kk], b0, acc0, 0,0,0);
        acc1 = __builtin_amdgcn_mfma_f32_16x16x32_f16(af[kk], b1, acc1, 0,0,0);
        acc2 = __builtin_amdgcn_mfma_f32_16x16x32_f16(af[kk], b2, acc2, 0,0,0);
        acc3 = __builtin_amdgcn_mfma_f32_16x16x32_f16(af[kk], b3, acc3, 0,0,0);
    }

    const int rowD = mw*16 + g*4;
    #pragma unroll
    for (int nf = 0; nf < 4; ++nf) {
        const f32x4& a = (nf==0)?acc0:(nf==1)?acc1:(nf==2)?acc2:acc3;
        int token = j0 + nf*16 + r;
        #pragma unroll
        for (int reg = 0; reg < 4; ++reg) {
            int row = m0 + rowD + reg;
            po[(size_t)(n*CC + row)*LL + token] = (_Float16)a[reg];
        }
    }
}

// ---------------- bilinear x2 upsample + bias + gamma + residual ----------------
__global__ void k_final(const float* __restrict__ x, const _Float16* __restrict__ po,
                        const float* __restrict__ bproj, const float* __restrict__ gammap,
                        float* __restrict__ out) {
    int idx = blockIdx.x*256 + threadIdx.x;
    if (idx >= NB*CC*96*96) return;
    int X = idx % 96, Y = (idx/96) % 96, o = (idx/(96*96)) % CC, n = idx/(96*96*CC);
    float gamma = gammap[0];
    float yf = Y*0.5f - 0.25f, xf = X*0.5f - 0.25f;
    float y0f = floorf(yf), x0f = floorf(xf);
    float tyy = yf - y0f, txx = xf - x0f;
    int y0 = (int)y0f, x0 = (int)x0f;
    int iy0 = max(y0,0), iy1 = min(y0+1,GG-1);
    int ix0 = max(x0,0), ix1 = min(x0+1,GG-1);
    const _Float16* pp = po + (size_t)(n*CC + o)*LL;
    float v00 = (float)pp[iy0*GG+ix0], v01 = (float)pp[iy0*GG+ix1];
    float v10 = (float)pp[iy1*GG+ix0], v11 = (float)pp[iy1*GG+ix1];
    float vy0 = v00 + txx*(v01-v00);
    float vy1 = v10 + txx*(v11-v10);
    float bil = vy0 + tyy*(vy1-vy0);
    out[idx] = gamma*(bil + bproj[o]) + x[idx];
}

extern "C" void kernel_launch(void* const* d_in, const int* in_sizes, int n_in,
                              void* d_out, int out_size, void* d_ws, size_t ws_size,
                              hipStream_t stream) {
    const float* x   = (const float*)d_in[0];
    const float* Wq  = (const float*)d_in[1];
    const float* Wk  = (const float*)d_in[2];
    const float* Wv  = (const float*)d_in[3];
    const float* Wgx = (const float*)d_in[4];
    const float* Wgy = (const float*)d_in[5];
    const float* ab  = (const float*)d_in[6];
    const float* Wp  = (const float*)d_in[7];
    const float* bp  = (const float*)d_in[8];
    const float* gm  = (const float*)d_in[9];
    float* ws = (float*)d_ws;
    _Float16* vbT = (_Float16*)(ws + OFF_VBT);
    _Float16* ebT = (_Float16*)(ws + OFF_EBT);
    float* qbp = ws + OFF_QB;
    _Float16* vtb = (_Float16*)(ws + OFF_VT);
    float* aop = ws + OFF_AO;
    _Float16* xh = (_Float16*)(ws + OFF_XH);   // aliases ao (dead until attn)
    float* ebp = ws + OFF_EB;
    float* ptxp= ws + OFF_PTX;
    float* ptyp= ws + OFF_PTY;
    float* wbp = ws + OFF_WB;
    _Float16* pop = (_Float16*)(ws + OFF_PO);  // fp16, aliases qb
    float* out = (float*)d_out;

    k_xin<<<dim3(LL/64, CC/64, NB), 256, 0, stream>>>(x, xh);
    k_prep<<<dim3(PTAB_N, 3), 256, 0, stream>>>(Wgx, Wgy, Wk, ab, ptxp, ptyp, wbp);
    k_gemm_qv<<<dim3(LL/64, 9, NB), 256, 0, stream>>>(Wq, Wv, wbp, xh, qbp, vtb, ebp);
    k_vtr<<<dim3(NB*HEADS, 6), 256, 0, stream>>>(vtb, ebp, vbT, ebT);
    k_attn<<<dim3(LL/64, NB*HEADS), 256, 0, stream>>>(qbp, vbT, ebT, ptxp, ptyp, aop);
    k_gemm_proj<<<dim3(LL/64, 4, NB), 256, 0, stream>>>(Wp, aop, pop);
    k_final<<<(NB*CC*96*96 + 255)/256, 256, 0, stream>>>(x, pop, bp, gm, out);
}

// Round 24
// 81.606 us; speedup vs baseline: 1.0632x; 1.0008x over previous
//
#include <hip/hip_runtime.h>
#include <math.h>

#define CC 256
#define HEADS 8
#define DD 32
#define GG 48
#define LL (GG*GG)      // 2304
#define NB 2
#define PTAB_N 95

typedef float f32x4 __attribute__((ext_vector_type(4)));
typedef _Float16 f16x8 __attribute__((ext_vector_type(8)));
typedef _Float16 f16x4 __attribute__((ext_vector_type(4)));

// workspace layout (floats).
// vbT/ebT live in the old xs region. xh aliases ao (dead before attn writes ao).
// po (fp16) aliases qb (qb dead after attn).
#define OFF_XS   0
#define SZ_XS    (NB*CC*LL)           // 1,179,648
#define OFF_VBT  OFF_XS               // 786,432 floats (fp16 x 1,572,864)
#define OFF_EBT  (OFF_XS + 786432)    // 24,576 floats (fp16 x 49,152)
#define OFF_QB   (OFF_XS + SZ_XS)
#define SZ_QB    (NB*LL*CC)           // 1,179,648
#define OFF_PO   OFF_QB
#define OFF_VT   (OFF_QB + SZ_QB)
#define SZ_VT_F  (NB*CC*LL/2)         // vtb fp16, 589,824 floats
#define OFF_AO   (OFF_VT + SZ_VT_F)
#define OFF_XH   OFF_AO               // xh fp16 aliases ao
#define SZ_AO    (NB*LL*CC)
#define OFF_EB   (OFF_AO + SZ_AO)
#define SZ_EB    (NB*HEADS*LL)
#define OFF_PTX  (OFF_EB + SZ_EB)
#define SZ_PT    (PTAB_N*CC)
#define OFF_PTY  (OFF_PTX + SZ_PT)
#define OFF_WB   (OFF_PTY + SZ_PT)

// ---------------- fused extract+convert: x (strided) -> xh fp16 swizzled ------
__global__ void k_xin(const float* __restrict__ x, _Float16* __restrict__ xh) {
    const int n = blockIdx.z, c0 = blockIdx.y*64, s0 = blockIdx.x*64;
    const int t = threadIdx.x;
    __shared__ _Float16 ldt[64*72];   // [s][c], row stride 72
    #pragma unroll
    for (int l = 0; l < 4; ++l) {
        int idx = t + 256*l;          // 0..1023
        int cl = idx >> 4, s4 = idx & 15;
        const float* xb = x + (size_t)(n*CC + c0+cl)*96*96;
        #pragma unroll
        for (int e = 0; e < 4; ++e) {
            int s = s0 + s4*4 + e;
            int h = s / GG, w = s % GG;
            ldt[(s4*4+e)*72 + cl] = (_Float16)xb[(2*h)*96 + 2*w];
        }
    }
    __syncthreads();
    #pragma unroll
    for (int l = 0; l < 2; ++l) {
        int idx = t + 256*l;          // 0..511
        int sl = idx >> 3, jg = idx & 7;
        f16x8 o = *(const f16x8*)(ldt + sl*72 + jg*8);
        int s = s0 + sl;
        int p = ((c0 >> 3) + jg) ^ (s & 7);
        *(f16x8*)(xh + (size_t)(n*LL + s)*CC + p*8) = o;
    }
}

// ---------------- merged prep: ptab (y=0,1) + wb (y=2, blocks 0..7) -----------
__global__ void k_prep(const float* __restrict__ Wgx, const float* __restrict__ Wgy,
                       const float* __restrict__ Wk, const float* __restrict__ ab,
                       float* __restrict__ ptx, float* __restrict__ pty,
                       float* __restrict__ wb) {
    const int which = blockIdx.y;
    const int t = threadIdx.x;
    if (which == 2) {
        int i = blockIdx.x;
        if (i < HEADS) {
            float acc = 0.f;
            for (int d = 0; d < DD; ++d) acc += ab[i*DD+d] * Wk[(i*DD+d)*CC + t];
            wb[i*CC + t] = acc;
        }
        return;
    }
    __shared__ float emb[128];
    int ddv = blockIdx.x;
    float diff = 2.0f * (float)(ddv - 47);
    if (t < 64) {
        float dim = powf(1000.0f, (float)t / 64.0f);
        float ang = diff / dim;
        emb[t]      = sinf(ang);
        emb[t + 64] = cosf(ang);
    }
    __syncthreads();
    const float* Wg = which ? Wgy : Wgx;
    float* pt = which ? pty : ptx;
    float acc = 0.f;
    #pragma unroll 8
    for (int e = 0; e < 128; ++e) acc += emb[e] * Wg[t*128 + e];
    pt[ddv*CC + t] = acc * 0.70710678118654752f;
}

// ---------------- MFMA GEMM: A=[Wq;Wv;wb;0] (576x256) @ xh^T -> qb/vtb/ebx ----
__global__ __launch_bounds__(256) void k_gemm_qv(const float* __restrict__ Wq,
                                                 const float* __restrict__ Wv,
                                                 const float* __restrict__ wb,
                                                 const _Float16* __restrict__ xh,
                                                 float* __restrict__ qb,
                                                 _Float16* __restrict__ vtb,
                                                 float* __restrict__ ebx) {
    const int n  = blockIdx.z;
    const int my = blockIdx.y;           // 0..8: m0 = my*64
    const int j0 = blockIdx.x * 64;      // token tile
    const int t = threadIdx.x;
    const int lane = t & 63, mw = t >> 6;
    __shared__ alignas(16) _Float16 As[64*256];
    __shared__ alignas(16) _Float16 Bs[64*256];

    #pragma unroll
    for (int l = 0; l < 8; ++l) {
        int idx = t + 256*l;             // 0..2047
        int m = idx >> 5, j = idx & 31;
        int row = my*64 + m;
        f16x8 h = {};
        if (row < 520) {
            const float* src = (row < 256) ? (Wq + (size_t)row*CC + j*8)
                             : (row < 512) ? (Wv + (size_t)(row-256)*CC + j*8)
                                           : (wb + (size_t)(row-512)*CC + j*8);
            float4 v0 = *(const float4*)(src);
            float4 v1 = *(const float4*)(src + 4);
            h[0]=(_Float16)v0.x; h[1]=(_Float16)v0.y;
            h[2]=(_Float16)v0.z; h[3]=(_Float16)v0.w;
            h[4]=(_Float16)v1.x; h[5]=(_Float16)v1.y;
            h[6]=(_Float16)v1.z; h[7]=(_Float16)v1.w;
        }
        *(f16x8*)(As + m*256 + ((j ^ (m&7))*8)) = h;
    }
    {
        const _Float16* src = xh + (size_t)(n*LL + j0)*CC + mw*4096 + lane*8;
        _Float16* dst = Bs + mw*4096;
        #pragma unroll
        for (int c = 0; c < 8; ++c)
            __builtin_amdgcn_global_load_lds(src + c*512, dst + c*512, 16, 0, 0);
    }
    __syncthreads();

    const int r = lane & 15, g = lane >> 4;
    f16x8 af[8];
    #pragma unroll
    for (int kk = 0; kk < 8; ++kk)
        af[kk] = *(const f16x8*)(As + (mw*16 + r)*256 + (((kk*4+g) ^ (r&7))*8));
    f32x4 acc0 = {}, acc1 = {}, acc2 = {}, acc3 = {};
    #pragma unroll
    for (int kk = 0; kk < 8; ++kk) {
        f16x8 b0 = *(const f16x8*)(Bs + (0*16 + r)*256 + (((kk*4+g) ^ (r&7))*8));
        f16x8 b1 = *(const f16x8*)(Bs + (1*16 + r)*256 + (((kk*4+g) ^ (r&7))*8));
        f16x8 b2 = *(const f16x8*)(Bs + (2*16 + r)*256 + (((kk*4+g) ^ (r&7))*8));
        f16x8 b3 = *(const f16x8*)(Bs + (3*16 + r)*256 + (((kk*4+g) ^ (r&7))*8));
        acc0 = __builtin_amdgcn_mfma_f32_16x16x32_f16(af[kk], b0, acc0, 0,0,0);
        acc1 = __builtin_amdgcn_mfma_f32_16x16x32_f16(af[kk], b1, acc1, 0,0,0);
        acc2 = __builtin_amdgcn_mfma_f32_16x16x32_f16(af[kk], b2, acc2, 0,0,0);
        acc3 = __builtin_amdgcn_mfma_f32_16x16x32_f16(af[kk], b3, acc3, 0,0,0);
    }

    const int rowD = mw*16 + g*4;
    #pragma unroll
    for (int nf = 0; nf < 4; ++nf) {
        const f32x4& a = (nf==0)?acc0:(nf==1)?acc1:(nf==2)?acc2:acc3;
        int token = j0 + nf*16 + r;
        #pragma unroll
        for (int reg = 0; reg < 4; ++reg) {
            int row = my*64 + rowD + reg;
            float v = a[reg];
            if (my < 4) {
                qb[(size_t)(n*LL + token)*CC + row] = v;
            } else if (my < 8) {
                vtb[(size_t)(n*CC + row - 256)*LL + token] = (_Float16)v;
            } else {
                int i = row - 512;
                if (i < 8) ebx[(size_t)(n*HEADS + i)*LL + token] = __expf(v);
            }
        }
    }
}

// ---------------- transpose V to u-contiguous, fold eb, XOR-swizzled ----------
__global__ void k_vtr(const _Float16* __restrict__ vtb, const float* __restrict__ ebx,
                      _Float16* __restrict__ vbT, _Float16* __restrict__ ebT) {
    const int ni = blockIdx.x;
    const int pair = blockIdx.y*256 + threadIdx.x;   // [0,1536)
    const int v = pair >> 5, d = pair & 31;
    const int sw = d & 7;
    const _Float16* vsrc = vtb + (size_t)(ni*32 + d)*LL;
    const float*  ebs  = ebx + (size_t)ni*LL;
    _Float16* dst = vbT + (size_t)ni*98304 + (size_t)(v*32 + d)*64;
    f16x8 z = {};
    #pragma unroll
    for (int c = 0; c < 6; ++c) {
        f16x8 o;
        #pragma unroll
        for (int e = 0; e < 8; ++e) {
            int u = c*8 + e;
            o[e] = (_Float16)((float)vsrc[u*48 + v] * ebs[u*48 + v]);
        }
        *(f16x8*)(dst + (c ^ sw)*8) = o;
    }
    *(f16x8*)(dst + (6 ^ sw)*8) = z;
    *(f16x8*)(dst + (7 ^ sw)*8) = z;
    if (d == 0) {
        _Float16* ed = ebT + (size_t)ni*3072 + (size_t)v*64;
        #pragma unroll
        for (int c = 0; c < 6; ++c) {
            f16x8 o;
            #pragma unroll
            for (int e = 0; e < 8; ++e)
                o[e] = (_Float16)ebs[(c*8+e)*48 + v];
            *(f16x8*)(ed + c*8) = o;
        }
        *(f16x8*)(ed + 48) = z;
        *(f16x8*)(ed + 56) = z;
    }
}

// ---------------- attention v7 (r17/r19-proven): dbuf gload_lds, fp16 Ey/Ex ---
__global__ __launch_bounds__(256) void k_attn(const float* __restrict__ qb,
                                              const _Float16* __restrict__ vbT,
                                              const _Float16* __restrict__ ebT,
                                              const float* __restrict__ ptx,
                                              const float* __restrict__ pty,
                                              float* __restrict__ ao) {
    const int t = threadIdx.x;
    const int lane = t & 63;
    const int mw = t >> 6;
    const int ni = blockIdx.y;
    const int n = ni >> 3, i = ni & 7;
    const int s0 = blockIdx.x * 64;

    // overlay pool: phase1 {qs 8KB, pts 15.2KB} / main {Vt dbuf 2x16KB}
    __shared__ alignas(16) char smpool[32768];
    float*    qs  = (float*)smpool;                 // [2048]
    _Float16* pts = (_Float16*)(smpool + 8192);     // [2][95][40]
    _Float16* Vt  = (_Float16*)smpool;              // [2][8192]
    __shared__ alignas(16) _Float16 Exs[64*56];     // exp(ex-mex) fp16, stride 56
    __shared__ alignas(16) _Float16 Eys[64*72];     // exp(ey-mey) fp16, u-pad 64

    // phase 0: stage Q tile + fp16 head-slices of pos tables
    #pragma unroll
    for (int l = 0; l < 2; ++l) {
        int f = t + 256*l;
        int r4 = f >> 3, dq = f & 7;
        float4 v4 = *(const float4*)(qb + (size_t)(n*LL + s0 + r4)*CC + i*32 + dq*4);
        *(float4*)(&qs[r4*32 + dq*4]) = v4;
    }
    for (int idx = t; idx < 2*PTAB_N*8; idx += 256) {
        int which = idx / (PTAB_N*8);
        int rem = idx % (PTAB_N*8);
        int ddv = rem >> 3, f4 = rem & 7;
        const float* src = (which ? ptx : pty) + (size_t)ddv*CC + i*32 + f4*4;
        float4 v = *(const float4*)src;
        f16x4 hh;
        hh[0]=(_Float16)v.x; hh[1]=(_Float16)v.y;
        hh[2]=(_Float16)v.z; hh[3]=(_Float16)v.w;
        *(f16x4*)(pts + which*(PTAB_N*40) + ddv*40 + f4*4) = hh;
    }
    __syncthreads();

    // phase 1: one q-row per thread-quad; raw ey/ex in registers; quad max
    {
        const int rr = t >> 2, pp = t & 3;
        const int s = s0 + rr, h = s / GG, w = s % GG;
        float4 qreg[8];
        #pragma unroll
        for (int d4 = 0; d4 < 8; ++d4) qreg[d4] = *(const float4*)(qs + rr*32 + d4*4);
        float eyv[12], exv[12];
        float mey = -1e30f, mex = -1e30f;
        #pragma unroll
        for (int k = 0; k < 24; ++k) {
            int j = pp + 4*k;
            const _Float16* tp;
            if (k < 12) tp = pts + (h - j + 47)*40;
            else        tp = pts + PTAB_N*40 + (w - (j-48) + 47)*40;
            float acc = 0.f;
            #pragma unroll
            for (int d8 = 0; d8 < 4; ++d8) {
                f16x8 b = *(const f16x8*)(tp + d8*8);
                float4 a1v = qreg[2*d8], a2v = qreg[2*d8+1];
                acc += a1v.x*(float)b[0] + a1v.y*(float)b[1]
                     + a1v.z*(float)b[2] + a1v.w*(float)b[3]
                     + a2v.x*(float)b[4] + a2v.y*(float)b[5]
                     + a2v.z*(float)b[6] + a2v.w*(float)b[7];
            }
            if (k < 12) { eyv[k] = acc;    mey = fmaxf(mey, acc); }
            else        { exv[k-12] = acc; mex = fmaxf(mex, acc); }
        }
        mey = fmaxf(mey, __shfl_xor(mey, 1, 64));
        mey = fmaxf(mey, __shfl_xor(mey, 2, 64));
        mex = fmaxf(mex, __shfl_xor(mex, 1, 64));
        mex = fmaxf(mex, __shfl_xor(mex, 2, 64));
        #pragma unroll
        for (int k = 0; k < 12; ++k) {
            Eys[rr*72 + pp + 4*k] = (_Float16)__expf(eyv[k] - mey);
            Exs[rr*56 + pp + 4*k] = (_Float16)__expf(exv[k] - mex);
        }
    }
    // zero-pad Ey u 48..63
    for (int zi = t; zi < 64*16; zi += 256) {
        int r = zi >> 4, c = zi & 15;
        Eys[r*72 + 48 + c] = (_Float16)0.f;
    }
    __syncthreads();

    const int r = lane & 15, g = lane >> 4;
    const int rowA = mw*16 + r;
    const int rowD = mw*16 + g*4;

    f16x8 a0 = *(const f16x8*)(Eys + rowA*72 + g*8);
    f16x8 a1 = *(const f16x8*)(Eys + rowA*72 + 32 + g*8);

    const _Float16* vb = vbT + (size_t)ni*(48*32*64);
    const _Float16* et = ebT + (size_t)ni*(48*64);

    // HS = Ey' @ ebT  (3 n-frags of 16 v)
    f32x4 hs0, hs1, hs2;
    {
        f32x4 zv = {0.f,0.f,0.f,0.f};
        f16x8 b0 = *(const f16x8*)(et + (0*16 + r)*64 + g*8);
        f16x8 b1 = *(const f16x8*)(et + (0*16 + r)*64 + 32 + g*8);
        hs0 = __builtin_amdgcn_mfma_f32_16x16x32_f16(a0, b0, zv, 0,0,0);
        hs0 = __builtin_amdgcn_mfma_f32_16x16x32_f16(a1, b1, hs0, 0,0,0);
        b0 = *(const f16x8*)(et + (1*16 + r)*64 + g*8);
        b1 = *(const f16x8*)(et + (1*16 + r)*64 + 32 + g*8);
        hs1 = __builtin_amdgcn_mfma_f32_16x16x32_f16(a0, b0, zv, 0,0,0);
        hs1 = __builtin_amdgcn_mfma_f32_16x16x32_f16(a1, b1, hs1, 0,0,0);
        b0 = *(const f16x8*)(et + (2*16 + r)*64 + g*8);
        b1 = *(const f16x8*)(et + (2*16 + r)*64 + 32 + g*8);
        hs2 = __builtin_amdgcn_mfma_f32_16x16x32_f16(a0, b0, zv, 0,0,0);
        hs2 = __builtin_amdgcn_mfma_f32_16x16x32_f16(a1, b1, hs2, 0,0,0);
    }
    // S[s] = sum_v Ex' * HS ; butterfly over 16 v-cols
    float Sp[4];
    #pragma unroll
    for (int reg = 0; reg < 4; ++reg) {
        Sp[reg] = (float)Exs[(rowD+reg)*56 +  0 + r] * hs0[reg]
                + (float)Exs[(rowD+reg)*56 + 16 + r] * hs1[reg]
                + (float)Exs[(rowD+reg)*56 + 32 + r] * hs2[reg];
    }
    #pragma unroll
    for (int m = 1; m <= 8; m <<= 1) {
        #pragma unroll
        for (int reg = 0; reg < 4; ++reg)
            Sp[reg] += __shfl_xor(Sp[reg], m, 64);
    }

    #define STAGE(BUF, TT) { \
        const _Float16* src_ = vb + (size_t)(TT)*8192 + mw*2048 + lane*8; \
        _Float16* dst_ = Vt + (BUF)*8192 + mw*2048; \
        __builtin_amdgcn_global_load_lds(src_,        dst_,        16, 0, 0); \
        __builtin_amdgcn_global_load_lds(src_ + 512,  dst_ + 512,  16, 0, 0); \
        __builtin_amdgcn_global_load_lds(src_ + 1024, dst_ + 1024, 16, 0, 0); \
        __builtin_amdgcn_global_load_lds(src_ + 1536, dst_ + 1536, 16, 0, 0); }

    f32x4 oacc0 = {0.f,0.f,0.f,0.f}, oacc1 = {0.f,0.f,0.f,0.f};
    const int sw0 = (g ^ (r&7))*8;
    const int sw1 = ((g+4) ^ (r&7))*8;
    int buf = 0;
    STAGE(0, 0);
    __syncthreads();
    #pragma unroll 1
    for (int tt = 0; tt < 12; ++tt) {
        if (tt < 11) STAGE(buf^1, tt+1);
        const _Float16* VB = Vt + buf*8192;
        const int v0 = tt*4;
        f16x4 exh0 = *(const f16x4*)(Exs + (rowD+0)*56 + v0);
        f16x4 exh1 = *(const f16x4*)(Exs + (rowD+1)*56 + v0);
        f16x4 exh2 = *(const f16x4*)(Exs + (rowD+2)*56 + v0);
        f16x4 exh3 = *(const f16x4*)(Exs + (rowD+3)*56 + v0);
        #pragma unroll
        for (int q = 0; q < 8; ++q) {
            const int vl = q >> 1, dh = q & 1;
            const int row = vl*32 + dh*16 + r;
            f16x8 b0 = *(const f16x8*)(VB + row*64 + sw0);
            f16x8 b1 = *(const f16x8*)(VB + row*64 + sw1);
            float e0 = (float)exh0[vl];
            float e1 = (float)exh1[vl];
            float e2 = (float)exh2[vl];
            float e3 = (float)exh3[vl];
            f32x4 hz = {0.f,0.f,0.f,0.f};
            hz = __builtin_amdgcn_mfma_f32_16x16x32_f16(a0, b0, hz, 0,0,0);
            hz = __builtin_amdgcn_mfma_f32_16x16x32_f16(a1, b1, hz, 0,0,0);
            if (dh == 0) {
                oacc0[0] += e0*hz[0]; oacc0[1] += e1*hz[1];
                oacc0[2] += e2*hz[2]; oacc0[3] += e3*hz[3];
            } else {
                oacc1[0] += e0*hz[0]; oacc1[1] += e1*hz[1];
                oacc1[2] += e2*hz[2]; oacc1[3] += e3*hz[3];
            }
        }
        __syncthreads();
        buf ^= 1;
    }

    #pragma unroll
    for (int reg = 0; reg < 4; ++reg) {
        float inv = 1.0f / fmaxf(Sp[reg], 1e-30f);
        size_t base = (size_t)(n*LL + s0 + rowD + reg)*CC + i*32;
        ao[base + r]      = oacc0[reg] * inv;
        ao[base + 16 + r] = oacc1[reg] * inv;
    }
}

// ---------------- MFMA proj GEMM: Wp(256x256) @ ao^T -> po fp16 ---------------
__global__ __launch_bounds__(256) void k_gemm_proj(const float* __restrict__ Wp,
                                                   const float* __restrict__ ao,
                                                   _Float16* __restrict__ po) {
    const int n  = blockIdx.z;
    const int m0 = blockIdx.y * 64;
    const int j0 = blockIdx.x * 64;
    const int t = threadIdx.x;
    const int lane = t & 63, mw = t >> 6;
    __shared__ alignas(16) _Float16 As[64*256];
    __shared__ alignas(16) _Float16 Bs[64*256];

    #pragma unroll
    for (int l = 0; l < 8; ++l) {
        int idx = t + 256*l;
        int m = idx >> 5, j = idx & 31;
        const float* srcA = Wp + (size_t)(m0 + m)*CC + j*8;
        float4 a0v = *(const float4*)srcA;
        float4 a1v = *(const float4*)(srcA + 4);
        f16x8 ha;
        ha[0]=(_Float16)a0v.x; ha[1]=(_Float16)a0v.y;
        ha[2]=(_Float16)a0v.z; ha[3]=(_Float16)a0v.w;
        ha[4]=(_Float16)a1v.x; ha[5]=(_Float16)a1v.y;
        ha[6]=(_Float16)a1v.z; ha[7]=(_Float16)a1v.w;
        *(f16x8*)(As + m*256 + ((j ^ (m&7))*8)) = ha;
        const float* srcB = ao + (size_t)(n*LL + j0 + m)*CC + j*8;
        float4 b0v = *(const float4*)srcB;
        float4 b1v = *(const float4*)(srcB + 4);
        f16x8 hb;
        hb[0]=(_Float16)b0v.x; hb[1]=(_Float16)b0v.y;
        hb[2]=(_Float16)b0v.z; hb[3]=(_Float16)b0v.w;
        hb[4]=(_Float16)b1v.x; hb[5]=(_Float16)b1v.y;
        hb[6]=(_Float16)b1v.z; hb[7]=(_Float16)b1v.w;
        *(f16x8*)(Bs + m*256 + ((j ^ (m&7))*8)) = hb;
    }
    __syncthreads();

    const int r = lane & 15, g = lane >> 4;
    f16x8 af[8];
    #pragma unroll
    for (int kk = 0; kk < 8; ++kk)
        af[kk] = *(const f16x8*)(As + (mw*16 + r)*256 + (((kk*4+g) ^ (r&7))*8));
    f32x4 acc0 = {}, acc1 = {}, acc2 = {}, acc3 = {};
    #pragma unroll
    for (int kk = 0; kk < 8; ++kk) {
        f16x8 b0 = *(const f16x8*)(Bs + (0*16 + r)*256 + (((kk*4+g) ^ (r&7))*8));
        f16x8 b1 = *(const f16x8*)(Bs + (1*16 + r)*256 + (((kk*4+g) ^ (r&7))*8));
        f16x8 b2 = *(const f16x8*)(Bs + (2*16 + r)*256 + (((kk*4+g) ^ (r&7))*8));
        f16x8 b3 = *(const f16x8*)(Bs + (3*16 + r)*256 + (((kk*4+g) ^ (r&7))*8));
        acc0 = __builtin_amdgcn_mfma_f32_16x16x32_f16(af[kk], b0, acc0, 0,0,0);
        acc1 = __builtin_amdgcn_mfma_f32_16x16x32_f16(af[kk], b1, acc1, 0,0,0);
        acc2 = __builtin_amdgcn_mfma_f32_16x16x32_f16(af[kk], b2, acc2, 0,0,0);
        acc3 = __builtin_amdgcn_mfma_f32_16x16x32_f16(af[kk], b3, acc3, 0,0,0);
    }

    const int rowD = mw*16 + g*4;
    #pragma unroll
    for (int nf = 0; nf < 4; ++nf) {
        const f32x4& a = (nf==0)?acc0:(nf==1)?acc1:(nf==2)?acc2:acc3;
        int token = j0 + nf*16 + r;
        #pragma unroll
        for (int reg = 0; reg < 4; ++reg) {
            int row = m0 + rowD + reg;
            po[(size_t)(n*CC + row)*LL + token] = (_Float16)a[reg];
        }
    }
}

// ---------------- bilinear x2 upsample + bias + gamma + residual ----------------
__global__ void k_final(const float* __restrict__ x, const _Float16* __restrict__ po,
                        const float* __restrict__ bproj, const float* __restrict__ gammap,
                        float* __restrict__ out) {
    int idx = blockIdx.x*256 + threadIdx.x;
    if (idx >= NB*CC*96*96) return;
    int X = idx % 96, Y = (idx/96) % 96, o = (idx/(96*96)) % CC, n = idx/(96*96*CC);
    float gamma = gammap[0];
    float yf = Y*0.5f - 0.25f, xf = X*0.5f - 0.25f;
    float y0f = floorf(yf), x0f = floorf(xf);
    float tyy = yf - y0f, txx = xf - x0f;
    int y0 = (int)y0f, x0 = (int)x0f;
    int iy0 = max(y0,0), iy1 = min(y0+1,GG-1);
    int ix0 = max(x0,0), ix1 = min(x0+1,GG-1);
    const _Float16* pp = po + (size_t)(n*CC + o)*LL;
    float v00 = (float)pp[iy0*GG+ix0], v01 = (float)pp[iy0*GG+ix1];
    float v10 = (float)pp[iy1*GG+ix0], v11 = (float)pp[iy1*GG+ix1];
    float vy0 = v00 + txx*(v01-v00);
    float vy1 = v10 + txx*(v11-v10);
    float bil = vy0 + tyy*(vy1-vy0);
    out[idx] = gamma*(bil + bproj[o]) + x[idx];
}

extern "C" void kernel_launch(void* const* d_in, const int* in_sizes, int n_in,
                              void* d_out, int out_size, void* d_ws, size_t ws_size,
                              hipStream_t stream) {
    const float* x   = (const float*)d_in[0];
    const float* Wq  = (const float*)d_in[1];
    const float* Wk  = (const float*)d_in[2];
    const float* Wv  = (const float*)d_in[3];
    const float* Wgx = (const float*)d_in[4];
    const float* Wgy = (const float*)d_in[5];
    const float* ab  = (const float*)d_in[6];
    const float* Wp  = (const float*)d_in[7];
    const float* bp  = (const float*)d_in[8];
    const float* gm  = (const float*)d_in[9];
    float* ws = (float*)d_ws;
    _Float16* vbT = (_Float16*)(ws + OFF_VBT);
    _Float16* ebT = (_Float16*)(ws + OFF_EBT);
    float* qbp = ws + OFF_QB;
    _Float16* vtb = (_Float16*)(ws + OFF_VT);
    float* aop = ws + OFF_AO;
    _Float16* xh = (_Float16*)(ws + OFF_XH);   // aliases ao (dead until attn)
    float* ebp = ws + OFF_EB;
    float* ptxp= ws + OFF_PTX;
    float* ptyp= ws + OFF_PTY;
    float* wbp = ws + OFF_WB;
    _Float16* pop = (_Float16*)(ws + OFF_PO);  // fp16, aliases qb
    float* out = (float*)d_out;

    k_xin<<<dim3(LL/64, CC/64, NB), 256, 0, stream>>>(x, xh);
    k_prep<<<dim3(PTAB_N, 3), 256, 0, stream>>>(Wgx, Wgy, Wk, ab, ptxp, ptyp, wbp);
    k_gemm_qv<<<dim3(LL/64, 9, NB), 256, 0, stream>>>(Wq, Wv, wbp, xh, qbp, vtb, ebp);
    k_vtr<<<dim3(NB*HEADS, 6), 256, 0, stream>>>(vtb, ebp, vbT, ebT);
    k_attn<<<dim3(LL/64, NB*HEADS), 256, 0, stream>>>(qbp, vbT, ebT, ptxp, ptyp, aop);
    k_gemm_proj<<<dim3(LL/64, 4, NB), 256, 0, stream>>>(Wp, aop, pop);
    k_final<<<(NB*CC*96*96 + 255)/256, 256, 0, stream>>>(x, pop, bp, gm, out);
}